// Round 12
// baseline (723.041 us; speedup 1.0000x reference)
//
#include <hip/hip_runtime.h>
#include <stdint.h>

typedef __attribute__((ext_vector_type(8))) short bf16x8;
typedef __attribute__((ext_vector_type(4))) float f32x4;
typedef __attribute__((ext_vector_type(8))) unsigned short us8;
typedef __attribute__((ext_vector_type(2))) unsigned int u32x2;
typedef __bf16 bf16v2 __attribute__((ext_vector_type(2)));

#define T_CNT 1048576
#define E_CNT 262144

static __device__ __forceinline__ unsigned short f2bf_u(float f) {
  __bf16 h = (__bf16)f;
  return __builtin_bit_cast(unsigned short, h);
}
static __device__ __forceinline__ uint32_t pack2bf(float a, float b) {
  bf16v2 t; t[0] = (__bf16)a; t[1] = (__bf16)b;
  return __builtin_bit_cast(uint32_t, t);
}
static __device__ __forceinline__ float silu_f(float v) {
  float e = __builtin_amdgcn_exp2f(v * -1.44269504088896341f);
  return v * __builtin_amdgcn_rcpf(1.0f + e);
}
static __device__ __forceinline__ bf16x8 frag8(f32x4 a, f32x4 b) {
  union { bf16x8 v; uint32_t u[4]; } r;
  r.u[0] = pack2bf(a[0], a[1]); r.u[1] = pack2bf(a[2], a[3]);
  r.u[2] = pack2bf(b[0], b[1]); r.u[3] = pack2bf(b[2], b[3]);
  return r.v;
}

// ---------------------------------------------------------------------------
// mlp4 (R8 form) — used by edge kernel and the fused fallback only.
// 4 waves, wave w owns cols [w*32,+32); x shared in xbA/xbB with barriers.
// ---------------------------------------------------------------------------
static __device__ __forceinline__ void mlp4(
    char* __restrict__ xbA, char* __restrict__ xbB,
    const char* __restrict__ wt4,
    const float* __restrict__ b1, const float* __restrict__ b2,
    const float* __restrict__ b3, float* __restrict__ outT,
    int l15, int q, int w, int rs)
{
  const int cb = w * 32;
  #pragma unroll
  for (int L = 0; L < 4; ++L) {
    const char* src = (L & 1) ? xbB : xbA;
    char* dst = (L & 1) ? xbA : xbB;
    bf16x8 wf[2][4];
    #pragma unroll
    for (int ct = 0; ct < 2; ++ct)
      #pragma unroll
      for (int ks = 0; ks < 4; ++ks)
        wf[ct][ks] = *(const bf16x8*)(wt4 + (L << 15) + (((w * 2 + ct) * 4 + ks) << 10) + (l15 | (q << 4)) * 16);
    if (L < 3) {
      const float* bp = (L == 0) ? b1 : (L == 1) ? b2 : b3;
      f32x4 bv0 = *(const f32x4*)(bp + cb + q * 4);
      f32x4 bv1 = *(const f32x4*)(bp + cb + 16 + q * 4);
      #pragma unroll
      for (int rg = 0; rg < 4; ++rg) {
        const int row = rg * 16 + l15;
        f32x4 acc0 = {0.f,0.f,0.f,0.f}, acc1 = {0.f,0.f,0.f,0.f};
        #pragma unroll
        for (int ks = 0; ks < 4; ++ks) {
          bf16x8 xf = *(const bf16x8*)(src + ((row * 256 + ks * 64 + q * 16) ^ rs));
          acc0 = __builtin_amdgcn_mfma_f32_16x16x32_bf16(wf[0][ks], xf, acc0, 0, 0, 0);
          acc1 = __builtin_amdgcn_mfma_f32_16x16x32_bf16(wf[1][ks], xf, acc1, 0, 0, 0);
        }
        uint2 u0, u1;
        u0.x = pack2bf(silu_f(acc0[0] + bv0[0]), silu_f(acc0[1] + bv0[1]));
        u0.y = pack2bf(silu_f(acc0[2] + bv0[2]), silu_f(acc0[3] + bv0[3]));
        u1.x = pack2bf(silu_f(acc1[0] + bv1[0]), silu_f(acc1[1] + bv1[1]));
        u1.y = pack2bf(silu_f(acc1[2] + bv1[2]), silu_f(acc1[3] + bv1[3]));
        *(uint2*)(dst + ((row * 256 + w * 64 + q * 8) ^ rs)) = u0;
        *(uint2*)(dst + ((row * 256 + w * 64 + 32 + q * 8) ^ rs)) = u1;
      }
      __syncthreads();
    } else {
      #pragma unroll
      for (int rg = 0; rg < 4; ++rg) {
        const int row = rg * 16 + l15;
        f32x4 acc0 = {0.f,0.f,0.f,0.f}, acc1 = {0.f,0.f,0.f,0.f};
        #pragma unroll
        for (int ks = 0; ks < 4; ++ks) {
          bf16x8 xf = *(const bf16x8*)(src + ((row * 256 + ks * 64 + q * 16) ^ rs));
          acc0 = __builtin_amdgcn_mfma_f32_16x16x32_bf16(wf[0][ks], xf, acc0, 0, 0, 0);
          acc1 = __builtin_amdgcn_mfma_f32_16x16x32_bf16(wf[1][ks], xf, acc1, 0, 0, 0);
        }
        float* op = outT + (size_t)row * 128 + cb + q * 4;
        __builtin_nontemporal_store(acc0, (f32x4*)(op));
        __builtin_nontemporal_store(acc1, (f32x4*)(op + 16));
      }
    }
  }
}

// ---------------------------------------------------------------------------
// A: angle projection (barrier-free, unchanged from R11).
// x0 layout: grow*256 + ((c*32 + q*8) ^ rs) — the LDS-image layout.
// ---------------------------------------------------------------------------
__global__ __launch_bounds__(256) void angle_proj_kernel(
    const float* __restrict__ m_ji, const float* __restrict__ a_sbf,
    const int* __restrict__ kj, const int* __restrict__ ji,
    const char* __restrict__ waT, char* __restrict__ x0)
{
  const int tid = threadIdx.x, lane = tid & 63, w = tid >> 6;
  const int l15 = lane & 15, q = lane >> 4;
  const int rs = (l15 & 7) << 4;
  const size_t tb = (size_t)blockIdx.x * 64;
  const int rl = w * 16 + l15;
  const size_t grow = tb + rl;

  const int ikj = kj[grow], iji = ji[grow];
  const float* bk = m_ji + (size_t)ikj * 128 + q * 4;
  const float* bj = m_ji + (size_t)iji * 128 + q * 4;

  f32x4 pk[4], pj[4];
  #pragma unroll
  for (int g = 0; g < 4; ++g) {
    pk[g] = *(const f32x4*)(bk + g * 16);
    pj[g] = *(const f32x4*)(bj + g * 16);
  }

  const float* ap = a_sbf + grow * 42;
  f32x4 a0 = *(const f32x4*)(ap + q * 8);
  f32x4 a1 = *(const f32x4*)(ap + q * 8 + 4);
  f32x4 c0 = {0.f,0.f,0.f,0.f}, c1 = {0.f,0.f,0.f,0.f};
  if (q == 0) { c0 = *(const f32x4*)(ap + 32); c1 = *(const f32x4*)(ap + 36); }
  else if (q == 1) { float2 t = *(const float2*)(ap + 40); c0[0] = t.x; c0[1] = t.y; }
  bf16x8 f0 = frag8(a0, a1);
  bf16x8 f1 = frag8(c0, c1);

  char* xrow = x0 + grow * 256;
  #pragma unroll
  for (int c = 0; c < 8; ++c) {
    bf16x8 wa0 = *(const bf16x8*)(waT + ((c * 2 + 0) << 10) + lane * 16);
    bf16x8 wa1 = *(const bf16x8*)(waT + ((c * 2 + 1) << 10) + lane * 16);
    f32x4 acc = {0.f,0.f,0.f,0.f};
    acc = __builtin_amdgcn_mfma_f32_16x16x32_bf16(wa0, f0, acc, 0, 0, 0);
    acc = __builtin_amdgcn_mfma_f32_16x16x32_bf16(wa1, f1, acc, 0, 0, 0);
    f32x4 g = pk[c & 3] + pj[c & 3];
    if (c < 4) {
      pk[c & 3] = *(const f32x4*)(bk + (c + 4) * 16);
      pj[c & 3] = *(const f32x4*)(bj + (c + 4) * 16);
    }
    u32x2 u;
    u[0] = pack2bf(acc[0] * g[0], acc[1] * g[1]);
    u[1] = pack2bf(acc[2] * g[2], acc[3] * g[3]);
    __builtin_nontemporal_store(u, (u32x2*)(xrow + ((c * 32 + q * 8) ^ rs)));
  }
}

// ---------------------------------------------------------------------------
// B: angle MLP — BARRIER-FREE wave-autonomous. 128-thread blocks (2 waves);
// wave owns 32 rows with a private 8KB LDS slice (no __syncthreads at all;
// same-wave DS ordering guarantees layer RAW). Per layer: read ALL x-frags
// into regs up front (32 VGPRs), then ct-outer weight streaming from L2-hot
// ws frags. Layer 1 reads x0 straight from global (no staging phase).
// ---------------------------------------------------------------------------
__global__ __launch_bounds__(128) void angle_mlp_kernel(
    const char* __restrict__ x0,
    const float* __restrict__ b1, const float* __restrict__ b2,
    const float* __restrict__ b3,
    const char* __restrict__ wt4, float* __restrict__ out)
{
  __shared__ __align__(16) char sl[16384];
  const int tid = threadIdx.x, lane = tid & 63, w = tid >> 6;
  const int l15 = lane & 15, q = lane >> 4;
  const int rs = (l15 & 7) << 4;
  char* slice = sl + w * 8192;
  const size_t grow0 = ((size_t)blockIdx.x * 2 + w) * 32;
  const int lane16 = lane * 16;

  bf16x8 xf[2][4];
  #pragma unroll
  for (int rg = 0; rg < 2; ++rg)
    #pragma unroll
    for (int ks = 0; ks < 4; ++ks)
      xf[rg][ks] = *(const bf16x8*)(
          x0 + (grow0 + rg * 16 + l15) * 256 + ((ks * 64 + q * 16) ^ rs));

  #pragma unroll
  for (int L = 0; L < 4; ++L) {
    const char* wbase = wt4 + (L << 15);
    if (L > 0) {
      #pragma unroll
      for (int rg = 0; rg < 2; ++rg)
        #pragma unroll
        for (int ks = 0; ks < 4; ++ks)
          xf[rg][ks] = *(const bf16x8*)(
              slice + (((rg * 16 + l15) * 256 + ks * 64 + q * 16) ^ rs));
    }
    if (L < 3) {
      const float* bp = (L == 0) ? b1 : (L == 1) ? b2 : b3;
      #pragma unroll
      for (int ct = 0; ct < 8; ++ct) {
        bf16x8 wf0 = *(const bf16x8*)(wbase + ((ct * 4 + 0) << 10) + lane16);
        bf16x8 wf1 = *(const bf16x8*)(wbase + ((ct * 4 + 1) << 10) + lane16);
        bf16x8 wf2 = *(const bf16x8*)(wbase + ((ct * 4 + 2) << 10) + lane16);
        bf16x8 wf3 = *(const bf16x8*)(wbase + ((ct * 4 + 3) << 10) + lane16);
        f32x4 bv = *(const f32x4*)(bp + ct * 16 + q * 4);
        #pragma unroll
        for (int rg = 0; rg < 2; ++rg) {
          f32x4 acc = {0.f,0.f,0.f,0.f};
          acc = __builtin_amdgcn_mfma_f32_16x16x32_bf16(wf0, xf[rg][0], acc, 0, 0, 0);
          acc = __builtin_amdgcn_mfma_f32_16x16x32_bf16(wf1, xf[rg][1], acc, 0, 0, 0);
          acc = __builtin_amdgcn_mfma_f32_16x16x32_bf16(wf2, xf[rg][2], acc, 0, 0, 0);
          acc = __builtin_amdgcn_mfma_f32_16x16x32_bf16(wf3, xf[rg][3], acc, 0, 0, 0);
          uint2 u;
          u.x = pack2bf(silu_f(acc[0] + bv[0]), silu_f(acc[1] + bv[1]));
          u.y = pack2bf(silu_f(acc[2] + bv[2]), silu_f(acc[3] + bv[3]));
          *(uint2*)(slice + (((rg * 16 + l15) * 256 + ct * 32 + q * 8) ^ rs)) = u;
        }
      }
    } else {
      #pragma unroll
      for (int ct = 0; ct < 8; ++ct) {
        bf16x8 wf0 = *(const bf16x8*)(wbase + ((ct * 4 + 0) << 10) + lane16);
        bf16x8 wf1 = *(const bf16x8*)(wbase + ((ct * 4 + 1) << 10) + lane16);
        bf16x8 wf2 = *(const bf16x8*)(wbase + ((ct * 4 + 2) << 10) + lane16);
        bf16x8 wf3 = *(const bf16x8*)(wbase + ((ct * 4 + 3) << 10) + lane16);
        #pragma unroll
        for (int rg = 0; rg < 2; ++rg) {
          f32x4 acc = {0.f,0.f,0.f,0.f};
          acc = __builtin_amdgcn_mfma_f32_16x16x32_bf16(wf0, xf[rg][0], acc, 0, 0, 0);
          acc = __builtin_amdgcn_mfma_f32_16x16x32_bf16(wf1, xf[rg][1], acc, 0, 0, 0);
          acc = __builtin_amdgcn_mfma_f32_16x16x32_bf16(wf2, xf[rg][2], acc, 0, 0, 0);
          acc = __builtin_amdgcn_mfma_f32_16x16x32_bf16(wf3, xf[rg][3], acc, 0, 0, 0);
          __builtin_nontemporal_store(acc,
              (f32x4*)(out + (grow0 + rg * 16 + l15) * 128 + ct * 16 + q * 4));
        }
      }
    }
  }
}

// ---------------------------------------------------------------------------
// Fallback fused angle (R8 form) if ws is too small for x0.
// ---------------------------------------------------------------------------
__global__ __launch_bounds__(256) void angle_fused_kernel(
    const float* __restrict__ m_ji, const float* __restrict__ a_sbf,
    const int* __restrict__ kj, const int* __restrict__ ji,
    const float* __restrict__ b1, const float* __restrict__ b2,
    const float* __restrict__ b3,
    const char* __restrict__ wt4, const char* __restrict__ waT,
    float* __restrict__ out)
{
  __shared__ __align__(16) char xbA[16384];
  __shared__ __align__(16) char xbB[16384];
  const int tid = threadIdx.x, lane = tid & 63, w = tid >> 6;
  const int l15 = lane & 15, q = lane >> 4;
  const int rs = (l15 & 7) << 4;
  const size_t tb = (size_t)blockIdx.x * 64;
  const int cb = w * 32;

  bf16x8 wa[2][2];
  #pragma unroll
  for (int ct = 0; ct < 2; ++ct)
    #pragma unroll
    for (int ks = 0; ks < 2; ++ks)
      wa[ct][ks] = *(const bf16x8*)(waT + (((w * 2 + ct) * 2 + ks) << 10) + lane * 16);

  int ikj[4], iji[4];
  #pragma unroll
  for (int g = 0; g < 4; ++g) {
    ikj[g] = kj[tb + g * 16 + l15];
    iji[g] = ji[tb + g * 16 + l15];
  }
  f32x4 pk[2][2], pj[2][2];
  auto gissue = [&](int g) {
    const float* bk = m_ji + (size_t)ikj[g] * 128 + cb + q * 4;
    const float* bj = m_ji + (size_t)iji[g] * 128 + cb + q * 4;
    pk[g & 1][0] = *(const f32x4*)(bk);
    pk[g & 1][1] = *(const f32x4*)(bk + 16);
    pj[g & 1][0] = *(const f32x4*)(bj);
    pj[g & 1][1] = *(const f32x4*)(bj + 16);
  };
  gissue(0); gissue(1);

  #pragma unroll
  for (int rg = 0; rg < 4; ++rg) {
    const int row = rg * 16 + l15;
    const float* ap = a_sbf + (tb + row) * 42;
    f32x4 a0 = *(const f32x4*)(ap + q * 8);
    f32x4 a1 = *(const f32x4*)(ap + q * 8 + 4);
    f32x4 c0 = {0.f,0.f,0.f,0.f}, c1 = {0.f,0.f,0.f,0.f};
    if (q == 0) { c0 = *(const f32x4*)(ap + 32); c1 = *(const f32x4*)(ap + 36); }
    else if (q == 1) { float2 t = *(const float2*)(ap + 40); c0[0] = t.x; c0[1] = t.y; }
    bf16x8 f0 = frag8(a0, a1);
    bf16x8 f1 = frag8(c0, c1);
    f32x4 acc0 = {0.f,0.f,0.f,0.f}, acc1 = {0.f,0.f,0.f,0.f};
    acc0 = __builtin_amdgcn_mfma_f32_16x16x32_bf16(wa[0][0], f0, acc0, 0, 0, 0);
    acc0 = __builtin_amdgcn_mfma_f32_16x16x32_bf16(wa[0][1], f1, acc0, 0, 0, 0);
    acc1 = __builtin_amdgcn_mfma_f32_16x16x32_bf16(wa[1][0], f0, acc1, 0, 0, 0);
    acc1 = __builtin_amdgcn_mfma_f32_16x16x32_bf16(wa[1][1], f1, acc1, 0, 0, 0);
    f32x4 g0 = pk[rg & 1][0] + pj[rg & 1][0];
    f32x4 g1 = pk[rg & 1][1] + pj[rg & 1][1];
    if (rg < 2) gissue(rg + 2);
    uint2 u0, u1;
    u0.x = pack2bf(acc0[0] * g0[0], acc0[1] * g0[1]);
    u0.y = pack2bf(acc0[2] * g0[2], acc0[3] * g0[3]);
    u1.x = pack2bf(acc1[0] * g1[0], acc1[1] * g1[1]);
    u1.y = pack2bf(acc1[2] * g1[2], acc1[3] * g1[3]);
    *(uint2*)(xbA + ((row * 256 + w * 64 + q * 8) ^ rs)) = u0;
    *(uint2*)(xbA + ((row * 256 + w * 64 + 32 + q * 8) ^ rs)) = u1;
  }
  __syncthreads();

  mlp4(xbA, xbB, wt4, b1, b2, b3, out + tb * 128, l15, q, w, rs);
}

// ---------------------------------------------------------------------------
// Edge branch (R8 form, unchanged).
// ---------------------------------------------------------------------------
__global__ __launch_bounds__(256) void edge_kernel(
    const float* __restrict__ m_ji, const float* __restrict__ e_rbf,
    const float* __restrict__ b1, const float* __restrict__ b2,
    const float* __restrict__ b3,
    const char* __restrict__ wt4, const char* __restrict__ weT,
    float* __restrict__ out)
{
  __shared__ __align__(16) char xbA[16384];
  __shared__ __align__(16) char xbB[16384];
  const int tid = threadIdx.x, lane = tid & 63, w = tid >> 6;
  const int l15 = lane & 15, q = lane >> 4;
  const int rs = (l15 & 7) << 4;
  const size_t tb = (size_t)blockIdx.x * 64;
  const int cb = w * 32;

  bf16x8 we[2];
  #pragma unroll
  for (int ct = 0; ct < 2; ++ct)
    we[ct] = *(const bf16x8*)(weT + ((w * 2 + ct) << 10) + lane * 16);

  f32x4 mr[2][2];
  auto missue = [&](int g) {
    const float* bm = m_ji + (tb + g * 16 + l15) * 128 + cb + q * 4;
    mr[g & 1][0] = *(const f32x4*)(bm);
    mr[g & 1][1] = *(const f32x4*)(bm + 16);
  };
  missue(0); missue(1);

  #pragma unroll
  for (int rg = 0; rg < 4; ++rg) {
    const int row = rg * 16 + l15;
    const float* ep = e_rbf + (tb + row) * 6;
    f32x4 a0 = {0.f,0.f,0.f,0.f}, a1 = {0.f,0.f,0.f,0.f};
    if (q == 0) {
      a0 = *(const f32x4*)(ep);
      float2 t = *(const float2*)(ep + 4);
      a1[0] = t.x; a1[1] = t.y;
    }
    bf16x8 ef = frag8(a0, a1);
    f32x4 acc0 = {0.f,0.f,0.f,0.f}, acc1 = {0.f,0.f,0.f,0.f};
    acc0 = __builtin_amdgcn_mfma_f32_16x16x32_bf16(we[0], ef, acc0, 0, 0, 0);
    acc1 = __builtin_amdgcn_mfma_f32_16x16x32_bf16(we[1], ef, acc1, 0, 0, 0);
    f32x4 g0 = mr[rg & 1][0];
    f32x4 g1 = mr[rg & 1][1];
    if (rg < 2) missue(rg + 2);
    uint2 u0, u1;
    u0.x = pack2bf(acc0[0] * g0[0], acc0[1] * g0[1]);
    u0.y = pack2bf(acc0[2] * g0[2], acc0[3] * g0[3]);
    u1.x = pack2bf(acc1[0] * g1[0], acc1[1] * g1[1]);
    u1.y = pack2bf(acc1[2] * g1[2], acc1[3] * g1[3]);
    *(uint2*)(xbA + ((row * 256 + w * 64 + q * 8) ^ rs)) = u0;
    *(uint2*)(xbA + ((row * 256 + w * 64 + 32 + q * 8) ^ rs)) = u1;
  }
  __syncthreads();

  mlp4(xbA, xbB, wt4, b1, b2, b3, out + tb * 128, l15, q, w, rs);
}

// ---------------------------------------------------------------------------
// Prep: bf16 weights into fragment-linear layouts in d_ws (unchanged layout).
//  [0,128K):    edge W1..W4 frags [mat][ct*4+ks][lane]16B
//  [128K,256K): angle W1..W4 frags
//  [256K,272K): Wa proj frags [ct*2+ks][lane]  (K pad 42->64)
//  [272K,276K): We proj frags [ct][lane]       (K pad 6->32)
// frag(lane; n = ct*16+l15, k = ks*32+q*8+j) = W[k][n]
// ---------------------------------------------------------------------------
__global__ void prep_kernel(
    const float* __restrict__ W0, const float* __restrict__ W1,
    const float* __restrict__ W2, const float* __restrict__ W3,
    const float* __restrict__ W4, const float* __restrict__ W5,
    const float* __restrict__ W6, const float* __restrict__ W7,
    const float* __restrict__ Wa, const float* __restrict__ We,
    char* __restrict__ ws)
{
  const int gid = blockIdx.x * 256 + threadIdx.x;
  const int lane = gid & 63;
  const int l15 = lane & 15, q = lane >> 4;
  if (gid < 16384) {
    const int mat = gid >> 11;
    const int ctks = (gid & 2047) >> 6;
    const int n = (ctks >> 2) * 16 + l15;
    const int k0 = (ctks & 3) * 32 + q * 8;
    const float* W;
    switch (mat) {
      case 0: W = W0; break; case 1: W = W1; break;
      case 2: W = W2; break; case 3: W = W3; break;
      case 4: W = W4; break; case 5: W = W5; break;
      case 6: W = W6; break; default: W = W7; break;
    }
    us8 v;
    #pragma unroll
    for (int j = 0; j < 8; ++j) v[j] = f2bf_u(W[(size_t)(k0 + j) * 128 + n]);
    *(us8*)(ws + mat * 32768 + ctks * 1024 + lane * 16) = v;
  } else if (gid < 17408) {
    const int g = gid - 16384;
    const int ctks = g >> 6;
    const int n = (ctks >> 1) * 16 + l15;
    const int k0 = (ctks & 1) * 32 + q * 8;
    us8 v;
    #pragma unroll
    for (int j = 0; j < 8; ++j) {
      const int k = k0 + j;
      v[j] = (k < 42) ? f2bf_u(Wa[(size_t)k * 128 + n]) : (unsigned short)0;
    }
    *(us8*)(ws + 262144 + ctks * 1024 + lane * 16) = v;
  } else if (gid < 17920) {
    const int g = gid - 17408;
    const int ct = g >> 6;
    const int n = ct * 16 + l15;
    const int k0 = q * 8;
    us8 v;
    #pragma unroll
    for (int j = 0; j < 8; ++j) {
      const int k = k0 + j;
      v[j] = (k < 6) ? f2bf_u(We[(size_t)k * 128 + n]) : (unsigned short)0;
    }
    *(us8*)(ws + 278528 + ct * 1024 + lane * 16) = v;
  }
}

extern "C" void kernel_launch(void* const* d_in, const int* in_sizes, int n_in,
                              void* d_out, int out_size, void* d_ws, size_t ws_size,
                              hipStream_t stream) {
  (void)in_sizes; (void)n_in; (void)out_size;
  const float* m_ji  = (const float*)d_in[0];
  const float* e_rbf = (const float*)d_in[1];
  const float* a_sbf = (const float*)d_in[2];
  const int*   kj    = (const int*)d_in[4];
  const int*   ji    = (const int*)d_in[5];
  const float* We    = (const float*)d_in[6];
  const float* We1   = (const float*)d_in[7];
  const float* be1   = (const float*)d_in[8];
  const float* We2   = (const float*)d_in[9];
  const float* be2   = (const float*)d_in[10];
  const float* We3   = (const float*)d_in[11];
  const float* be3   = (const float*)d_in[12];
  const float* We4   = (const float*)d_in[13];
  const float* Wa    = (const float*)d_in[14];
  const float* Wa1   = (const float*)d_in[15];
  const float* ba1   = (const float*)d_in[16];
  const float* Wa2   = (const float*)d_in[17];
  const float* ba2   = (const float*)d_in[18];
  const float* Wa3   = (const float*)d_in[19];
  const float* ba3   = (const float*)d_in[20];
  const float* Wa4   = (const float*)d_in[21];
  char* ws = (char*)d_ws;
  float* out = (float*)d_out;
  float* out_a = out + (size_t)E_CNT * 128;

  prep_kernel<<<70, 256, 0, stream>>>(
      We1, We2, We3, We4, Wa1, Wa2, Wa3, Wa4, Wa, We, ws);
  edge_kernel<<<E_CNT / 64, 256, 0, stream>>>(
      m_ji, e_rbf, be1, be2, be3, ws, ws + 278528, out);

  const size_t x0_off = 1u << 20;
  const size_t need = x0_off + (size_t)T_CNT * 256;
  if (ws_size >= need) {
    char* x0 = ws + x0_off;
    angle_proj_kernel<<<T_CNT / 64, 256, 0, stream>>>(
        m_ji, a_sbf, kj, ji, ws + 262144, x0);
    angle_mlp_kernel<<<T_CNT / 64, 128, 0, stream>>>(
        x0, ba1, ba2, ba3, ws + 131072, out_a);
  } else {
    angle_fused_kernel<<<T_CNT / 64, 256, 0, stream>>>(
        m_ji, a_sbf, kj, ji, ba1, ba2, ba3, ws + 131072, ws + 262144, out_a);
  }
}

// Round 13
// 622.978 us; speedup vs baseline: 1.1606x; 1.1606x over previous
//
#include <hip/hip_runtime.h>
#include <stdint.h>

typedef __attribute__((ext_vector_type(8))) short bf16x8;
typedef __attribute__((ext_vector_type(4))) float f32x4;
typedef __attribute__((ext_vector_type(8))) unsigned short us8;
typedef __bf16 bf16v2 __attribute__((ext_vector_type(2)));

#define T_CNT 1048576
#define E_CNT 262144

static __device__ __forceinline__ unsigned short f2bf_u(float f) {
  __bf16 h = (__bf16)f;
  return __builtin_bit_cast(unsigned short, h);
}
static __device__ __forceinline__ uint32_t pack2bf(float a, float b) {
  bf16v2 t; t[0] = (__bf16)a; t[1] = (__bf16)b;
  return __builtin_bit_cast(uint32_t, t);
}
static __device__ __forceinline__ float silu_f(float v) {
  float e = __builtin_amdgcn_exp2f(v * -1.44269504088896341f);
  return v * __builtin_amdgcn_rcpf(1.0f + e);
}
static __device__ __forceinline__ bf16x8 frag8(f32x4 a, f32x4 b) {
  union { bf16x8 v; uint32_t u[4]; } r;
  r.u[0] = pack2bf(a[0], a[1]); r.u[1] = pack2bf(a[2], a[3]);
  r.u[2] = pack2bf(b[0], b[1]); r.u[3] = pack2bf(b[2], b[3]);
  return r.v;
}

// ---------------------------------------------------------------------------
// 4-layer MLP, register-liveness-bounded (the R13 fix): ct-outer with
// #pragma unroll 1 on layer/ct loops so the compiler cannot hoist weight
// loads across iterations (R5-R12: hoisting -> ~80 live regs -> scratch
// spills whose serial store->reload latency was ~50k cyc/block, the real
// bottleneck). Live set per point <= ~50 regs. 4 waves, wave w owns cols
// [w*32,+32); 64-row x tile ping-pongs in xbA/xbB (XOR-swizzled bf16).
// ---------------------------------------------------------------------------
static __device__ __forceinline__ void mlp4_lean(
    char* __restrict__ xbA, char* __restrict__ xbB,
    const char* __restrict__ wt4,
    const float* __restrict__ b1, const float* __restrict__ b2,
    const float* __restrict__ b3, float* __restrict__ outT,
    int l15, int q, int w, int rs)
{
  const int cb = w * 32;
  const int lane16 = (l15 | (q << 4)) * 16;
  const char* src = xbA;
  char* dst = xbB;

  #pragma unroll 1
  for (int L = 0; L < 3; ++L) {
    const char* wb = wt4 + (L << 15);
    const float* bp = (L == 0) ? b1 : (L == 1) ? b2 : b3;
    #pragma unroll 1
    for (int ct = 0; ct < 2; ++ct) {
      const char* wcb = wb + (((w * 2 + ct) * 4) << 10);
      bf16x8 wf0 = *(const bf16x8*)(wcb + lane16);
      bf16x8 wf1 = *(const bf16x8*)(wcb + 1024 + lane16);
      bf16x8 wf2 = *(const bf16x8*)(wcb + 2048 + lane16);
      bf16x8 wf3 = *(const bf16x8*)(wcb + 3072 + lane16);
      f32x4 bv = *(const f32x4*)(bp + cb + ct * 16 + q * 4);
      #pragma unroll
      for (int rg = 0; rg < 4; ++rg) {
        const int row = rg * 16 + l15;
        bf16x8 xf0 = *(const bf16x8*)(src + ((row * 256 + q * 16) ^ rs));
        bf16x8 xf1 = *(const bf16x8*)(src + ((row * 256 + 64 + q * 16) ^ rs));
        bf16x8 xf2 = *(const bf16x8*)(src + ((row * 256 + 128 + q * 16) ^ rs));
        bf16x8 xf3 = *(const bf16x8*)(src + ((row * 256 + 192 + q * 16) ^ rs));
        f32x4 acc = {0.f,0.f,0.f,0.f};
        acc = __builtin_amdgcn_mfma_f32_16x16x32_bf16(wf0, xf0, acc, 0, 0, 0);
        acc = __builtin_amdgcn_mfma_f32_16x16x32_bf16(wf1, xf1, acc, 0, 0, 0);
        acc = __builtin_amdgcn_mfma_f32_16x16x32_bf16(wf2, xf2, acc, 0, 0, 0);
        acc = __builtin_amdgcn_mfma_f32_16x16x32_bf16(wf3, xf3, acc, 0, 0, 0);
        uint2 u;
        u.x = pack2bf(silu_f(acc[0] + bv[0]), silu_f(acc[1] + bv[1]));
        u.y = pack2bf(silu_f(acc[2] + bv[2]), silu_f(acc[3] + bv[3]));
        *(uint2*)(dst + ((row * 256 + cb * 2 + ct * 32 + q * 8) ^ rs)) = u;
      }
    }
    __syncthreads();
    const char* t = src; src = dst; dst = (char*)t;
  }

  // last layer: f32 nt-store to global
  {
    const char* wb = wt4 + (3 << 15);
    #pragma unroll 1
    for (int ct = 0; ct < 2; ++ct) {
      const char* wcb = wb + (((w * 2 + ct) * 4) << 10);
      bf16x8 wf0 = *(const bf16x8*)(wcb + lane16);
      bf16x8 wf1 = *(const bf16x8*)(wcb + 1024 + lane16);
      bf16x8 wf2 = *(const bf16x8*)(wcb + 2048 + lane16);
      bf16x8 wf3 = *(const bf16x8*)(wcb + 3072 + lane16);
      #pragma unroll
      for (int rg = 0; rg < 4; ++rg) {
        const int row = rg * 16 + l15;
        bf16x8 xf0 = *(const bf16x8*)(src + ((row * 256 + q * 16) ^ rs));
        bf16x8 xf1 = *(const bf16x8*)(src + ((row * 256 + 64 + q * 16) ^ rs));
        bf16x8 xf2 = *(const bf16x8*)(src + ((row * 256 + 128 + q * 16) ^ rs));
        bf16x8 xf3 = *(const bf16x8*)(src + ((row * 256 + 192 + q * 16) ^ rs));
        f32x4 acc = {0.f,0.f,0.f,0.f};
        acc = __builtin_amdgcn_mfma_f32_16x16x32_bf16(wf0, xf0, acc, 0, 0, 0);
        acc = __builtin_amdgcn_mfma_f32_16x16x32_bf16(wf1, xf1, acc, 0, 0, 0);
        acc = __builtin_amdgcn_mfma_f32_16x16x32_bf16(wf2, xf2, acc, 0, 0, 0);
        acc = __builtin_amdgcn_mfma_f32_16x16x32_bf16(wf3, xf3, acc, 0, 0, 0);
        __builtin_nontemporal_store(acc,
            (f32x4*)(outT + (size_t)row * 128 + cb + ct * 16 + q * 4));
      }
    }
  }
}

// ---------------------------------------------------------------------------
// Angle branch (fused): proj rows strictly sequential (unroll 1) — per-row
// gather latency is exposed (~1k cyc x 4) but keeps live regs ~55; multi-
// block overlap hides it. Then the lean MLP.
// ---------------------------------------------------------------------------
__global__ __launch_bounds__(256) void angle_kernel(
    const float* __restrict__ m_ji, const float* __restrict__ a_sbf,
    const int* __restrict__ kj, const int* __restrict__ ji,
    const float* __restrict__ b1, const float* __restrict__ b2,
    const float* __restrict__ b3,
    const char* __restrict__ wt4, const char* __restrict__ waT,
    float* __restrict__ out)
{
  __shared__ __align__(16) char xbA[16384];
  __shared__ __align__(16) char xbB[16384];
  const int tid = threadIdx.x, lane = tid & 63, w = tid >> 6;
  const int l15 = lane & 15, q = lane >> 4;
  const int rs = (l15 & 7) << 4;
  const size_t tb = (size_t)blockIdx.x * 64;
  const int cb = w * 32;

  // persistent proj weight frags (16 regs)
  bf16x8 wa00 = *(const bf16x8*)(waT + (((w * 2 + 0) * 2 + 0) << 10) + lane * 16);
  bf16x8 wa01 = *(const bf16x8*)(waT + (((w * 2 + 0) * 2 + 1) << 10) + lane * 16);
  bf16x8 wa10 = *(const bf16x8*)(waT + (((w * 2 + 1) * 2 + 0) << 10) + lane * 16);
  bf16x8 wa11 = *(const bf16x8*)(waT + (((w * 2 + 1) * 2 + 1) << 10) + lane * 16);

  #pragma unroll 1
  for (int rg = 0; rg < 4; ++rg) {
    const int row = rg * 16 + l15;
    const size_t grow = tb + row;
    const int ikj = kj[grow], iji = ji[grow];
    // issue gathers early; a_sbf + frag-build covers part of the latency
    const float* bk = m_ji + (size_t)ikj * 128 + cb + q * 4;
    const float* bj = m_ji + (size_t)iji * 128 + cb + q * 4;
    f32x4 pk0 = *(const f32x4*)(bk);
    f32x4 pk1 = *(const f32x4*)(bk + 16);
    f32x4 pj0 = *(const f32x4*)(bj);
    f32x4 pj1 = *(const f32x4*)(bj + 16);

    const float* ap = a_sbf + grow * 42;
    f32x4 a0 = *(const f32x4*)(ap + q * 8);
    f32x4 a1 = *(const f32x4*)(ap + q * 8 + 4);
    f32x4 c0 = {0.f,0.f,0.f,0.f}, c1 = {0.f,0.f,0.f,0.f};
    if (q == 0) { c0 = *(const f32x4*)(ap + 32); c1 = *(const f32x4*)(ap + 36); }
    else if (q == 1) { float2 t = *(const float2*)(ap + 40); c0[0] = t.x; c0[1] = t.y; }
    bf16x8 f0 = frag8(a0, a1);
    bf16x8 f1 = frag8(c0, c1);

    f32x4 acc0 = {0.f,0.f,0.f,0.f}, acc1 = {0.f,0.f,0.f,0.f};
    acc0 = __builtin_amdgcn_mfma_f32_16x16x32_bf16(wa00, f0, acc0, 0, 0, 0);
    acc0 = __builtin_amdgcn_mfma_f32_16x16x32_bf16(wa01, f1, acc0, 0, 0, 0);
    acc1 = __builtin_amdgcn_mfma_f32_16x16x32_bf16(wa10, f0, acc1, 0, 0, 0);
    acc1 = __builtin_amdgcn_mfma_f32_16x16x32_bf16(wa11, f1, acc1, 0, 0, 0);

    f32x4 g0 = pk0 + pj0;
    f32x4 g1 = pk1 + pj1;
    uint2 u0, u1;
    u0.x = pack2bf(acc0[0] * g0[0], acc0[1] * g0[1]);
    u0.y = pack2bf(acc0[2] * g0[2], acc0[3] * g0[3]);
    u1.x = pack2bf(acc1[0] * g1[0], acc1[1] * g1[1]);
    u1.y = pack2bf(acc1[2] * g1[2], acc1[3] * g1[3]);
    *(uint2*)(xbA + ((row * 256 + cb * 2 + q * 8) ^ rs)) = u0;
    *(uint2*)(xbA + ((row * 256 + cb * 2 + 32 + q * 8) ^ rs)) = u1;
  }
  __syncthreads();

  mlp4_lean(xbA, xbB, wt4, b1, b2, b3, out + tb * 128, l15, q, w, rs);
}

// ---------------------------------------------------------------------------
// Edge branch: proj = (e_rbf @ We) * m_ji (K pad 6->32), then lean MLP.
// ---------------------------------------------------------------------------
__global__ __launch_bounds__(256) void edge_kernel(
    const float* __restrict__ m_ji, const float* __restrict__ e_rbf,
    const float* __restrict__ b1, const float* __restrict__ b2,
    const float* __restrict__ b3,
    const char* __restrict__ wt4, const char* __restrict__ weT,
    float* __restrict__ out)
{
  __shared__ __align__(16) char xbA[16384];
  __shared__ __align__(16) char xbB[16384];
  const int tid = threadIdx.x, lane = tid & 63, w = tid >> 6;
  const int l15 = lane & 15, q = lane >> 4;
  const int rs = (l15 & 7) << 4;
  const size_t tb = (size_t)blockIdx.x * 64;
  const int cb = w * 32;

  bf16x8 we0 = *(const bf16x8*)(weT + ((w * 2 + 0) << 10) + lane * 16);
  bf16x8 we1 = *(const bf16x8*)(weT + ((w * 2 + 1) << 10) + lane * 16);

  #pragma unroll 1
  for (int rg = 0; rg < 4; ++rg) {
    const int row = rg * 16 + l15;
    const size_t grow = tb + row;
    const float* bm = m_ji + grow * 128 + cb + q * 4;
    f32x4 m0 = *(const f32x4*)(bm);
    f32x4 m1 = *(const f32x4*)(bm + 16);

    const float* ep = e_rbf + grow * 6;
    f32x4 a0 = {0.f,0.f,0.f,0.f}, a1 = {0.f,0.f,0.f,0.f};
    if (q == 0) {
      a0 = *(const f32x4*)(ep);
      float2 t = *(const float2*)(ep + 4);
      a1[0] = t.x; a1[1] = t.y;
    }
    bf16x8 ef = frag8(a0, a1);

    f32x4 acc0 = {0.f,0.f,0.f,0.f}, acc1 = {0.f,0.f,0.f,0.f};
    acc0 = __builtin_amdgcn_mfma_f32_16x16x32_bf16(we0, ef, acc0, 0, 0, 0);
    acc1 = __builtin_amdgcn_mfma_f32_16x16x32_bf16(we1, ef, acc1, 0, 0, 0);

    uint2 u0, u1;
    u0.x = pack2bf(acc0[0] * m0[0], acc0[1] * m0[1]);
    u0.y = pack2bf(acc0[2] * m0[2], acc0[3] * m0[3]);
    u1.x = pack2bf(acc1[0] * m1[0], acc1[1] * m1[1]);
    u1.y = pack2bf(acc1[2] * m1[2], acc1[3] * m1[3]);
    *(uint2*)(xbA + ((row * 256 + cb * 2 + q * 8) ^ rs)) = u0;
    *(uint2*)(xbA + ((row * 256 + cb * 2 + 32 + q * 8) ^ rs)) = u1;
  }
  __syncthreads();

  mlp4_lean(xbA, xbB, wt4, b1, b2, b3, out + tb * 128, l15, q, w, rs);
}

// ---------------------------------------------------------------------------
// Prep: bf16 weights into fragment-linear layouts in d_ws (unchanged layout).
//  [0,128K):    edge W1..W4 frags [mat][ct*4+ks][lane]16B
//  [128K,256K): angle W1..W4 frags
//  [256K,272K): Wa proj frags [ct*2+ks][lane]  (K pad 42->64)
//  [272K,276K): We proj frags [ct][lane]       (K pad 6->32)
// frag(lane; n = ct*16+l15, k = ks*32+q*8+j) = W[k][n]
// ---------------------------------------------------------------------------
__global__ void prep_kernel(
    const float* __restrict__ W0, const float* __restrict__ W1,
    const float* __restrict__ W2, const float* __restrict__ W3,
    const float* __restrict__ W4, const float* __restrict__ W5,
    const float* __restrict__ W6, const float* __restrict__ W7,
    const float* __restrict__ Wa, const float* __restrict__ We,
    char* __restrict__ ws)
{
  const int gid = blockIdx.x * 256 + threadIdx.x;
  const int lane = gid & 63;
  const int l15 = lane & 15, q = lane >> 4;
  if (gid < 16384) {
    const int mat = gid >> 11;
    const int ctks = (gid & 2047) >> 6;
    const int n = (ctks >> 2) * 16 + l15;
    const int k0 = (ctks & 3) * 32 + q * 8;
    const float* W;
    switch (mat) {
      case 0: W = W0; break; case 1: W = W1; break;
      case 2: W = W2; break; case 3: W = W3; break;
      case 4: W = W4; break; case 5: W = W5; break;
      case 6: W = W6; break; default: W = W7; break;
    }
    us8 v;
    #pragma unroll
    for (int j = 0; j < 8; ++j) v[j] = f2bf_u(W[(size_t)(k0 + j) * 128 + n]);
    *(us8*)(ws + mat * 32768 + ctks * 1024 + lane * 16) = v;
  } else if (gid < 17408) {
    const int g = gid - 16384;
    const int ctks = g >> 6;
    const int n = (ctks >> 1) * 16 + l15;
    const int k0 = (ctks & 1) * 32 + q * 8;
    us8 v;
    #pragma unroll
    for (int j = 0; j < 8; ++j) {
      const int k = k0 + j;
      v[j] = (k < 42) ? f2bf_u(Wa[(size_t)k * 128 + n]) : (unsigned short)0;
    }
    *(us8*)(ws + 262144 + ctks * 1024 + lane * 16) = v;
  } else if (gid < 17920) {
    const int g = gid - 17408;
    const int ct = g >> 6;
    const int n = ct * 16 + l15;
    const int k0 = q * 8;
    us8 v;
    #pragma unroll
    for (int j = 0; j < 8; ++j) {
      const int k = k0 + j;
      v[j] = (k < 6) ? f2bf_u(We[(size_t)k * 128 + n]) : (unsigned short)0;
    }
    *(us8*)(ws + 278528 + ct * 1024 + lane * 16) = v;
  }
}

extern "C" void kernel_launch(void* const* d_in, const int* in_sizes, int n_in,
                              void* d_out, int out_size, void* d_ws, size_t ws_size,
                              hipStream_t stream) {
  (void)in_sizes; (void)n_in; (void)out_size; (void)ws_size;
  const float* m_ji  = (const float*)d_in[0];
  const float* e_rbf = (const float*)d_in[1];
  const float* a_sbf = (const float*)d_in[2];
  const int*   kj    = (const int*)d_in[4];
  const int*   ji    = (const int*)d_in[5];
  const float* We    = (const float*)d_in[6];
  const float* We1   = (const float*)d_in[7];
  const float* be1   = (const float*)d_in[8];
  const float* We2   = (const float*)d_in[9];
  const float* be2   = (const float*)d_in[10];
  const float* We3   = (const float*)d_in[11];
  const float* be3   = (const float*)d_in[12];
  const float* We4   = (const float*)d_in[13];
  const float* Wa    = (const float*)d_in[14];
  const float* Wa1   = (const float*)d_in[15];
  const float* ba1   = (const float*)d_in[16];
  const float* Wa2   = (const float*)d_in[17];
  const float* ba2   = (const float*)d_in[18];
  const float* Wa3   = (const float*)d_in[19];
  const float* ba3   = (const float*)d_in[20];
  const float* Wa4   = (const float*)d_in[21];
  char* ws = (char*)d_ws;
  float* out = (float*)d_out;
  float* out_a = out + (size_t)E_CNT * 128;

  prep_kernel<<<70, 256, 0, stream>>>(
      We1, We2, We3, We4, Wa1, Wa2, Wa3, Wa4, Wa, We, ws);
  edge_kernel<<<E_CNT / 64, 256, 0, stream>>>(
      m_ji, e_rbf, be1, be2, be3, ws, ws + 278528, out);
  angle_kernel<<<T_CNT / 64, 256, 0, stream>>>(
      m_ji, a_sbf, kj, ji, ba1, ba2, ba3, ws + 131072, ws + 262144, out_a);
}

// Round 14
// 602.159 us; speedup vs baseline: 1.2007x; 1.0346x over previous
//
#include <hip/hip_runtime.h>
#include <stdint.h>

typedef __attribute__((ext_vector_type(8))) short bf16x8;
typedef __attribute__((ext_vector_type(4))) float f32x4;
typedef __attribute__((ext_vector_type(8))) unsigned short us8;
typedef __bf16 bf16v2 __attribute__((ext_vector_type(2)));

#define T_CNT 1048576
#define E_CNT 262144

static __device__ __forceinline__ unsigned short f2bf_u(float f) {
  __bf16 h = (__bf16)f;
  return __builtin_bit_cast(unsigned short, h);
}
static __device__ __forceinline__ uint32_t pack2bf(float a, float b) {
  bf16v2 t; t[0] = (__bf16)a; t[1] = (__bf16)b;
  return __builtin_bit_cast(uint32_t, t);
}
static __device__ __forceinline__ float silu_f(float v) {
  float e = __builtin_amdgcn_exp2f(v * -1.44269504088896341f);
  return v * __builtin_amdgcn_rcpf(1.0f + e);
}
static __device__ __forceinline__ bf16x8 frag8(f32x4 a, f32x4 b) {
  union { bf16x8 v; uint32_t u[4]; } r;
  r.u[0] = pack2bf(a[0], a[1]); r.u[1] = pack2bf(a[2], a[3]);
  r.u[2] = pack2bf(b[0], b[1]); r.u[3] = pack2bf(b[2], b[3]);
  return r.v;
}

// ---------------------------------------------------------------------------
// R14: exact R8 structure with BM=32 (half tile, double blocks).
// 256 threads / 4 waves; wave w owns cols [w*32,+32); 32-row x tile
// ping-pongs in xbA/xbB (8KB each -> 16KB/block; thread-cap 8 blocks/CU).
// Per layer: wf[2][4] upfront (R8-proven), rg 0..1.
// ---------------------------------------------------------------------------
static __device__ __forceinline__ void mlp4(
    char* __restrict__ xbA, char* __restrict__ xbB,
    const char* __restrict__ wt4,
    const float* __restrict__ b1, const float* __restrict__ b2,
    const float* __restrict__ b3, float* __restrict__ outT,
    int l15, int q, int w, int rs)
{
  const int cb = w * 32;
  #pragma unroll
  for (int L = 0; L < 4; ++L) {
    const char* src = (L & 1) ? xbB : xbA;
    char* dst = (L & 1) ? xbA : xbB;
    bf16x8 wf[2][4];
    #pragma unroll
    for (int ct = 0; ct < 2; ++ct)
      #pragma unroll
      for (int ks = 0; ks < 4; ++ks)
        wf[ct][ks] = *(const bf16x8*)(wt4 + (L << 15) + (((w * 2 + ct) * 4 + ks) << 10) + (l15 | (q << 4)) * 16);
    if (L < 3) {
      const float* bp = (L == 0) ? b1 : (L == 1) ? b2 : b3;
      f32x4 bv0 = *(const f32x4*)(bp + cb + q * 4);
      f32x4 bv1 = *(const f32x4*)(bp + cb + 16 + q * 4);
      #pragma unroll
      for (int rg = 0; rg < 2; ++rg) {
        const int row = rg * 16 + l15;
        f32x4 acc0 = {0.f,0.f,0.f,0.f}, acc1 = {0.f,0.f,0.f,0.f};
        #pragma unroll
        for (int ks = 0; ks < 4; ++ks) {
          bf16x8 xf = *(const bf16x8*)(src + ((row * 256 + ks * 64 + q * 16) ^ rs));
          acc0 = __builtin_amdgcn_mfma_f32_16x16x32_bf16(wf[0][ks], xf, acc0, 0, 0, 0);
          acc1 = __builtin_amdgcn_mfma_f32_16x16x32_bf16(wf[1][ks], xf, acc1, 0, 0, 0);
        }
        uint2 u0, u1;
        u0.x = pack2bf(silu_f(acc0[0] + bv0[0]), silu_f(acc0[1] + bv0[1]));
        u0.y = pack2bf(silu_f(acc0[2] + bv0[2]), silu_f(acc0[3] + bv0[3]));
        u1.x = pack2bf(silu_f(acc1[0] + bv1[0]), silu_f(acc1[1] + bv1[1]));
        u1.y = pack2bf(silu_f(acc1[2] + bv1[2]), silu_f(acc1[3] + bv1[3]));
        *(uint2*)(dst + ((row * 256 + w * 64 + q * 8) ^ rs)) = u0;
        *(uint2*)(dst + ((row * 256 + w * 64 + 32 + q * 8) ^ rs)) = u1;
      }
      __syncthreads();
    } else {
      #pragma unroll
      for (int rg = 0; rg < 2; ++rg) {
        const int row = rg * 16 + l15;
        f32x4 acc0 = {0.f,0.f,0.f,0.f}, acc1 = {0.f,0.f,0.f,0.f};
        #pragma unroll
        for (int ks = 0; ks < 4; ++ks) {
          bf16x8 xf = *(const bf16x8*)(src + ((row * 256 + ks * 64 + q * 16) ^ rs));
          acc0 = __builtin_amdgcn_mfma_f32_16x16x32_bf16(wf[0][ks], xf, acc0, 0, 0, 0);
          acc1 = __builtin_amdgcn_mfma_f32_16x16x32_bf16(wf[1][ks], xf, acc1, 0, 0, 0);
        }
        float* op = outT + (size_t)row * 128 + cb + q * 4;
        __builtin_nontemporal_store(acc0, (f32x4*)(op));
        __builtin_nontemporal_store(acc1, (f32x4*)(op + 16));
      }
    }
  }
}

// ---------------------------------------------------------------------------
// Angle branch: 32-row tiles; all gathers issued upfront (2 rg rounds).
// ---------------------------------------------------------------------------
__global__ __launch_bounds__(256) void angle_kernel(
    const float* __restrict__ m_ji, const float* __restrict__ a_sbf,
    const int* __restrict__ kj, const int* __restrict__ ji,
    const float* __restrict__ b1, const float* __restrict__ b2,
    const float* __restrict__ b3,
    const char* __restrict__ wt4, const char* __restrict__ waT,
    float* __restrict__ out)
{
  __shared__ __align__(16) char xbA[8192];
  __shared__ __align__(16) char xbB[8192];
  const int tid = threadIdx.x, lane = tid & 63, w = tid >> 6;
  const int l15 = lane & 15, q = lane >> 4;
  const int rs = (l15 & 7) << 4;
  const size_t tb = (size_t)blockIdx.x * 32;
  const int cb = w * 32;

  bf16x8 wa[2][2];
  #pragma unroll
  for (int ct = 0; ct < 2; ++ct)
    #pragma unroll
    for (int ks = 0; ks < 2; ++ks)
      wa[ct][ks] = *(const bf16x8*)(waT + (((w * 2 + ct) * 2 + ks) << 10) + lane * 16);

  int ikj[2], iji[2];
  #pragma unroll
  for (int g = 0; g < 2; ++g) {
    ikj[g] = kj[tb + g * 16 + l15];
    iji[g] = ji[tb + g * 16 + l15];
  }
  // issue ALL gathers upfront (32 regs in flight); latency hides under the
  // a_sbf frag builds + proj MFMAs of rg 0
  f32x4 pk[2][2], pj[2][2];
  #pragma unroll
  for (int g = 0; g < 2; ++g) {
    const float* bk = m_ji + (size_t)ikj[g] * 128 + cb + q * 4;
    const float* bj = m_ji + (size_t)iji[g] * 128 + cb + q * 4;
    pk[g][0] = *(const f32x4*)(bk);
    pk[g][1] = *(const f32x4*)(bk + 16);
    pj[g][0] = *(const f32x4*)(bj);
    pj[g][1] = *(const f32x4*)(bj + 16);
  }

  #pragma unroll
  for (int rg = 0; rg < 2; ++rg) {
    const int row = rg * 16 + l15;
    const float* ap = a_sbf + (tb + row) * 42;
    f32x4 a0 = *(const f32x4*)(ap + q * 8);
    f32x4 a1 = *(const f32x4*)(ap + q * 8 + 4);
    f32x4 c0 = {0.f,0.f,0.f,0.f}, c1 = {0.f,0.f,0.f,0.f};
    if (q == 0) { c0 = *(const f32x4*)(ap + 32); c1 = *(const f32x4*)(ap + 36); }
    else if (q == 1) { float2 t = *(const float2*)(ap + 40); c0[0] = t.x; c0[1] = t.y; }
    bf16x8 f0 = frag8(a0, a1);
    bf16x8 f1 = frag8(c0, c1);
    f32x4 acc0 = {0.f,0.f,0.f,0.f}, acc1 = {0.f,0.f,0.f,0.f};
    acc0 = __builtin_amdgcn_mfma_f32_16x16x32_bf16(wa[0][0], f0, acc0, 0, 0, 0);
    acc0 = __builtin_amdgcn_mfma_f32_16x16x32_bf16(wa[0][1], f1, acc0, 0, 0, 0);
    acc1 = __builtin_amdgcn_mfma_f32_16x16x32_bf16(wa[1][0], f0, acc1, 0, 0, 0);
    acc1 = __builtin_amdgcn_mfma_f32_16x16x32_bf16(wa[1][1], f1, acc1, 0, 0, 0);
    f32x4 g0 = pk[rg][0] + pj[rg][0];
    f32x4 g1 = pk[rg][1] + pj[rg][1];
    uint2 u0, u1;
    u0.x = pack2bf(acc0[0] * g0[0], acc0[1] * g0[1]);
    u0.y = pack2bf(acc0[2] * g0[2], acc0[3] * g0[3]);
    u1.x = pack2bf(acc1[0] * g1[0], acc1[1] * g1[1]);
    u1.y = pack2bf(acc1[2] * g1[2], acc1[3] * g1[3]);
    *(uint2*)(xbA + ((row * 256 + w * 64 + q * 8) ^ rs)) = u0;
    *(uint2*)(xbA + ((row * 256 + w * 64 + 32 + q * 8) ^ rs)) = u1;
  }
  __syncthreads();

  mlp4(xbA, xbB, wt4, b1, b2, b3, out + tb * 128, l15, q, w, rs);
}

// ---------------------------------------------------------------------------
// Edge branch: 32-row tiles; m_ji rows streamed upfront.
// ---------------------------------------------------------------------------
__global__ __launch_bounds__(256) void edge_kernel(
    const float* __restrict__ m_ji, const float* __restrict__ e_rbf,
    const float* __restrict__ b1, const float* __restrict__ b2,
    const float* __restrict__ b3,
    const char* __restrict__ wt4, const char* __restrict__ weT,
    float* __restrict__ out)
{
  __shared__ __align__(16) char xbA[8192];
  __shared__ __align__(16) char xbB[8192];
  const int tid = threadIdx.x, lane = tid & 63, w = tid >> 6;
  const int l15 = lane & 15, q = lane >> 4;
  const int rs = (l15 & 7) << 4;
  const size_t tb = (size_t)blockIdx.x * 32;
  const int cb = w * 32;

  bf16x8 we[2];
  #pragma unroll
  for (int ct = 0; ct < 2; ++ct)
    we[ct] = *(const bf16x8*)(weT + ((w * 2 + ct) << 10) + lane * 16);

  f32x4 mr[2][2];
  #pragma unroll
  for (int g = 0; g < 2; ++g) {
    const float* bm = m_ji + (tb + g * 16 + l15) * 128 + cb + q * 4;
    mr[g][0] = *(const f32x4*)(bm);
    mr[g][1] = *(const f32x4*)(bm + 16);
  }

  #pragma unroll
  for (int rg = 0; rg < 2; ++rg) {
    const int row = rg * 16 + l15;
    const float* ep = e_rbf + (tb + row) * 6;
    f32x4 a0 = {0.f,0.f,0.f,0.f}, a1 = {0.f,0.f,0.f,0.f};
    if (q == 0) {
      a0 = *(const f32x4*)(ep);
      float2 t = *(const float2*)(ep + 4);
      a1[0] = t.x; a1[1] = t.y;
    }
    bf16x8 ef = frag8(a0, a1);
    f32x4 acc0 = {0.f,0.f,0.f,0.f}, acc1 = {0.f,0.f,0.f,0.f};
    acc0 = __builtin_amdgcn_mfma_f32_16x16x32_bf16(we[0], ef, acc0, 0, 0, 0);
    acc1 = __builtin_amdgcn_mfma_f32_16x16x32_bf16(we[1], ef, acc1, 0, 0, 0);
    f32x4 g0 = mr[rg][0];
    f32x4 g1 = mr[rg][1];
    uint2 u0, u1;
    u0.x = pack2bf(acc0[0] * g0[0], acc0[1] * g0[1]);
    u0.y = pack2bf(acc0[2] * g0[2], acc0[3] * g0[3]);
    u1.x = pack2bf(acc1[0] * g1[0], acc1[1] * g1[1]);
    u1.y = pack2bf(acc1[2] * g1[2], acc1[3] * g1[3]);
    *(uint2*)(xbA + ((row * 256 + w * 64 + q * 8) ^ rs)) = u0;
    *(uint2*)(xbA + ((row * 256 + w * 64 + 32 + q * 8) ^ rs)) = u1;
  }
  __syncthreads();

  mlp4(xbA, xbB, wt4, b1, b2, b3, out + tb * 128, l15, q, w, rs);
}

// ---------------------------------------------------------------------------
// Prep: bf16 weights into fragment-linear layouts in d_ws (unchanged layout).
//  [0,128K):    edge W1..W4 frags [mat][ct*4+ks][lane]16B
//  [128K,256K): angle W1..W4 frags
//  [256K,272K): Wa proj frags [ct*2+ks][lane]  (K pad 42->64)
//  [272K,276K): We proj frags [ct][lane]       (K pad 6->32)
// frag(lane; n = ct*16+l15, k = ks*32+q*8+j) = W[k][n]
// ---------------------------------------------------------------------------
__global__ void prep_kernel(
    const float* __restrict__ W0, const float* __restrict__ W1,
    const float* __restrict__ W2, const float* __restrict__ W3,
    const float* __restrict__ W4, const float* __restrict__ W5,
    const float* __restrict__ W6, const float* __restrict__ W7,
    const float* __restrict__ Wa, const float* __restrict__ We,
    char* __restrict__ ws)
{
  const int gid = blockIdx.x * 256 + threadIdx.x;
  const int lane = gid & 63;
  const int l15 = lane & 15, q = lane >> 4;
  if (gid < 16384) {
    const int mat = gid >> 11;
    const int ctks = (gid & 2047) >> 6;
    const int n = (ctks >> 2) * 16 + l15;
    const int k0 = (ctks & 3) * 32 + q * 8;
    const float* W;
    switch (mat) {
      case 0: W = W0; break; case 1: W = W1; break;
      case 2: W = W2; break; case 3: W = W3; break;
      case 4: W = W4; break; case 5: W = W5; break;
      case 6: W = W6; break; default: W = W7; break;
    }
    us8 v;
    #pragma unroll
    for (int j = 0; j < 8; ++j) v[j] = f2bf_u(W[(size_t)(k0 + j) * 128 + n]);
    *(us8*)(ws + mat * 32768 + ctks * 1024 + lane * 16) = v;
  } else if (gid < 17408) {
    const int g = gid - 16384;
    const int ctks = g >> 6;
    const int n = (ctks >> 1) * 16 + l15;
    const int k0 = (ctks & 1) * 32 + q * 8;
    us8 v;
    #pragma unroll
    for (int j = 0; j < 8; ++j) {
      const int k = k0 + j;
      v[j] = (k < 42) ? f2bf_u(Wa[(size_t)k * 128 + n]) : (unsigned short)0;
    }
    *(us8*)(ws + 262144 + ctks * 1024 + lane * 16) = v;
  } else if (gid < 17920) {
    const int g = gid - 17408;
    const int ct = g >> 6;
    const int n = ct * 16 + l15;
    const int k0 = q * 8;
    us8 v;
    #pragma unroll
    for (int j = 0; j < 8; ++j) {
      const int k = k0 + j;
      v[j] = (k < 6) ? f2bf_u(We[(size_t)k * 128 + n]) : (unsigned short)0;
    }
    *(us8*)(ws + 278528 + ct * 1024 + lane * 16) = v;
  }
}

extern "C" void kernel_launch(void* const* d_in, const int* in_sizes, int n_in,
                              void* d_out, int out_size, void* d_ws, size_t ws_size,
                              hipStream_t stream) {
  (void)in_sizes; (void)n_in; (void)out_size; (void)ws_size;
  const float* m_ji  = (const float*)d_in[0];
  const float* e_rbf = (const float*)d_in[1];
  const float* a_sbf = (const float*)d_in[2];
  const int*   kj    = (const int*)d_in[4];
  const int*   ji    = (const int*)d_in[5];
  const float* We    = (const float*)d_in[6];
  const float* We1   = (const float*)d_in[7];
  const float* be1   = (const float*)d_in[8];
  const float* We2   = (const float*)d_in[9];
  const float* be2   = (const float*)d_in[10];
  const float* We3   = (const float*)d_in[11];
  const float* be3   = (const float*)d_in[12];
  const float* We4   = (const float*)d_in[13];
  const float* Wa    = (const float*)d_in[14];
  const float* Wa1   = (const float*)d_in[15];
  const float* ba1   = (const float*)d_in[16];
  const float* Wa2   = (const float*)d_in[17];
  const float* ba2   = (const float*)d_in[18];
  const float* Wa3   = (const float*)d_in[19];
  const float* ba3   = (const float*)d_in[20];
  const float* Wa4   = (const float*)d_in[21];
  char* ws = (char*)d_ws;
  float* out = (float*)d_out;
  float* out_a = out + (size_t)E_CNT * 128;

  prep_kernel<<<70, 256, 0, stream>>>(
      We1, We2, We3, We4, Wa1, Wa2, Wa3, Wa4, Wa, We, ws);
  edge_kernel<<<E_CNT / 32, 256, 0, stream>>>(
      m_ji, e_rbf, be1, be2, be3, ws, ws + 278528, out);
  angle_kernel<<<T_CNT / 32, 256, 0, stream>>>(
      m_ji, a_sbf, kj, ji, ba1, ba2, ba3, ws + 131072, ws + 262144, out_a);
}

// Round 15
// 583.957 us; speedup vs baseline: 1.2382x; 1.0312x over previous
//
#include <hip/hip_runtime.h>
#include <stdint.h>

typedef __attribute__((ext_vector_type(8))) short bf16x8;
typedef __attribute__((ext_vector_type(4))) float f32x4;
typedef __attribute__((ext_vector_type(8))) unsigned short us8;
typedef __bf16 bf16v2 __attribute__((ext_vector_type(2)));

#define T_CNT 1048576
#define E_CNT 262144

static __device__ __forceinline__ unsigned short f2bf_u(float f) {
  __bf16 h = (__bf16)f;
  return __builtin_bit_cast(unsigned short, h);
}
static __device__ __forceinline__ uint32_t pack2bf(float a, float b) {
  bf16v2 t; t[0] = (__bf16)a; t[1] = (__bf16)b;
  return __builtin_bit_cast(uint32_t, t);
}
static __device__ __forceinline__ float silu_f(float v) {
  float e = __builtin_amdgcn_exp2f(v * -1.44269504088896341f);
  return v * __builtin_amdgcn_rcpf(1.0f + e);
}
static __device__ __forceinline__ bf16x8 frag8(f32x4 a, f32x4 b) {
  union { bf16x8 v; uint32_t u[4]; } r;
  r.u[0] = pack2bf(a[0], a[1]); r.u[1] = pack2bf(a[2], a[3]);
  r.u[2] = pack2bf(b[0], b[1]); r.u[3] = pack2bf(b[2], b[3]);
  return r.v;
}

// ---------------------------------------------------------------------------
// R15 = R14 structure with __launch_bounds__(256, 4): 2nd arg (min waves/EU)
// raises the VGPR budget 64 -> 128 so the allocator stops spilling (R5-R14:
// WRITE_SIZE excess 73-222 MiB = scratch traffic; scratch both serialized
// the critical path and capped co-residency at ~3.6 blocks/CU despite
// LDS/thread headroom for 8).
// 256 threads / 4 waves; wave w owns cols [w*32,+32); 32-row x tile
// ping-pongs in xbA/xbB (8KB each).
// ---------------------------------------------------------------------------
static __device__ __forceinline__ void mlp4(
    char* __restrict__ xbA, char* __restrict__ xbB,
    const char* __restrict__ wt4,
    const float* __restrict__ b1, const float* __restrict__ b2,
    const float* __restrict__ b3, float* __restrict__ outT,
    int l15, int q, int w, int rs)
{
  const int cb = w * 32;
  #pragma unroll
  for (int L = 0; L < 4; ++L) {
    const char* src = (L & 1) ? xbB : xbA;
    char* dst = (L & 1) ? xbA : xbB;
    bf16x8 wf[2][4];
    #pragma unroll
    for (int ct = 0; ct < 2; ++ct)
      #pragma unroll
      for (int ks = 0; ks < 4; ++ks)
        wf[ct][ks] = *(const bf16x8*)(wt4 + (L << 15) + (((w * 2 + ct) * 4 + ks) << 10) + (l15 | (q << 4)) * 16);
    if (L < 3) {
      const float* bp = (L == 0) ? b1 : (L == 1) ? b2 : b3;
      f32x4 bv0 = *(const f32x4*)(bp + cb + q * 4);
      f32x4 bv1 = *(const f32x4*)(bp + cb + 16 + q * 4);
      #pragma unroll
      for (int rg = 0; rg < 2; ++rg) {
        const int row = rg * 16 + l15;
        f32x4 acc0 = {0.f,0.f,0.f,0.f}, acc1 = {0.f,0.f,0.f,0.f};
        #pragma unroll
        for (int ks = 0; ks < 4; ++ks) {
          bf16x8 xf = *(const bf16x8*)(src + ((row * 256 + ks * 64 + q * 16) ^ rs));
          acc0 = __builtin_amdgcn_mfma_f32_16x16x32_bf16(wf[0][ks], xf, acc0, 0, 0, 0);
          acc1 = __builtin_amdgcn_mfma_f32_16x16x32_bf16(wf[1][ks], xf, acc1, 0, 0, 0);
        }
        uint2 u0, u1;
        u0.x = pack2bf(silu_f(acc0[0] + bv0[0]), silu_f(acc0[1] + bv0[1]));
        u0.y = pack2bf(silu_f(acc0[2] + bv0[2]), silu_f(acc0[3] + bv0[3]));
        u1.x = pack2bf(silu_f(acc1[0] + bv1[0]), silu_f(acc1[1] + bv1[1]));
        u1.y = pack2bf(silu_f(acc1[2] + bv1[2]), silu_f(acc1[3] + bv1[3]));
        *(uint2*)(dst + ((row * 256 + w * 64 + q * 8) ^ rs)) = u0;
        *(uint2*)(dst + ((row * 256 + w * 64 + 32 + q * 8) ^ rs)) = u1;
      }
      __syncthreads();
    } else {
      #pragma unroll
      for (int rg = 0; rg < 2; ++rg) {
        const int row = rg * 16 + l15;
        f32x4 acc0 = {0.f,0.f,0.f,0.f}, acc1 = {0.f,0.f,0.f,0.f};
        #pragma unroll
        for (int ks = 0; ks < 4; ++ks) {
          bf16x8 xf = *(const bf16x8*)(src + ((row * 256 + ks * 64 + q * 16) ^ rs));
          acc0 = __builtin_amdgcn_mfma_f32_16x16x32_bf16(wf[0][ks], xf, acc0, 0, 0, 0);
          acc1 = __builtin_amdgcn_mfma_f32_16x16x32_bf16(wf[1][ks], xf, acc1, 0, 0, 0);
        }
        float* op = outT + (size_t)row * 128 + cb + q * 4;
        __builtin_nontemporal_store(acc0, (f32x4*)(op));
        __builtin_nontemporal_store(acc1, (f32x4*)(op + 16));
      }
    }
  }
}

// ---------------------------------------------------------------------------
// Angle branch: 32-row tiles; all gathers issued upfront (2 rg rounds).
// ---------------------------------------------------------------------------
__global__ __launch_bounds__(256, 4) void angle_kernel(
    const float* __restrict__ m_ji, const float* __restrict__ a_sbf,
    const int* __restrict__ kj, const int* __restrict__ ji,
    const float* __restrict__ b1, const float* __restrict__ b2,
    const float* __restrict__ b3,
    const char* __restrict__ wt4, const char* __restrict__ waT,
    float* __restrict__ out)
{
  __shared__ __align__(16) char xbA[8192];
  __shared__ __align__(16) char xbB[8192];
  const int tid = threadIdx.x, lane = tid & 63, w = tid >> 6;
  const int l15 = lane & 15, q = lane >> 4;
  const int rs = (l15 & 7) << 4;
  const size_t tb = (size_t)blockIdx.x * 32;
  const int cb = w * 32;

  bf16x8 wa[2][2];
  #pragma unroll
  for (int ct = 0; ct < 2; ++ct)
    #pragma unroll
    for (int ks = 0; ks < 2; ++ks)
      wa[ct][ks] = *(const bf16x8*)(waT + (((w * 2 + ct) * 2 + ks) << 10) + lane * 16);

  int ikj[2], iji[2];
  #pragma unroll
  for (int g = 0; g < 2; ++g) {
    ikj[g] = kj[tb + g * 16 + l15];
    iji[g] = ji[tb + g * 16 + l15];
  }
  // issue ALL gathers upfront (32 regs in flight); latency hides under the
  // a_sbf frag builds + proj MFMAs of rg 0
  f32x4 pk[2][2], pj[2][2];
  #pragma unroll
  for (int g = 0; g < 2; ++g) {
    const float* bk = m_ji + (size_t)ikj[g] * 128 + cb + q * 4;
    const float* bj = m_ji + (size_t)iji[g] * 128 + cb + q * 4;
    pk[g][0] = *(const f32x4*)(bk);
    pk[g][1] = *(const f32x4*)(bk + 16);
    pj[g][0] = *(const f32x4*)(bj);
    pj[g][1] = *(const f32x4*)(bj + 16);
  }

  #pragma unroll
  for (int rg = 0; rg < 2; ++rg) {
    const int row = rg * 16 + l15;
    const float* ap = a_sbf + (tb + row) * 42;
    f32x4 a0 = *(const f32x4*)(ap + q * 8);
    f32x4 a1 = *(const f32x4*)(ap + q * 8 + 4);
    f32x4 c0 = {0.f,0.f,0.f,0.f}, c1 = {0.f,0.f,0.f,0.f};
    if (q == 0) { c0 = *(const f32x4*)(ap + 32); c1 = *(const f32x4*)(ap + 36); }
    else if (q == 1) { float2 t = *(const float2*)(ap + 40); c0[0] = t.x; c0[1] = t.y; }
    bf16x8 f0 = frag8(a0, a1);
    bf16x8 f1 = frag8(c0, c1);
    f32x4 acc0 = {0.f,0.f,0.f,0.f}, acc1 = {0.f,0.f,0.f,0.f};
    acc0 = __builtin_amdgcn_mfma_f32_16x16x32_bf16(wa[0][0], f0, acc0, 0, 0, 0);
    acc0 = __builtin_amdgcn_mfma_f32_16x16x32_bf16(wa[0][1], f1, acc0, 0, 0, 0);
    acc1 = __builtin_amdgcn_mfma_f32_16x16x32_bf16(wa[1][0], f0, acc1, 0, 0, 0);
    acc1 = __builtin_amdgcn_mfma_f32_16x16x32_bf16(wa[1][1], f1, acc1, 0, 0, 0);
    f32x4 g0 = pk[rg][0] + pj[rg][0];
    f32x4 g1 = pk[rg][1] + pj[rg][1];
    uint2 u0, u1;
    u0.x = pack2bf(acc0[0] * g0[0], acc0[1] * g0[1]);
    u0.y = pack2bf(acc0[2] * g0[2], acc0[3] * g0[3]);
    u1.x = pack2bf(acc1[0] * g1[0], acc1[1] * g1[1]);
    u1.y = pack2bf(acc1[2] * g1[2], acc1[3] * g1[3]);
    *(uint2*)(xbA + ((row * 256 + w * 64 + q * 8) ^ rs)) = u0;
    *(uint2*)(xbA + ((row * 256 + w * 64 + 32 + q * 8) ^ rs)) = u1;
  }
  __syncthreads();

  mlp4(xbA, xbB, wt4, b1, b2, b3, out + tb * 128, l15, q, w, rs);
}

// ---------------------------------------------------------------------------
// Edge branch: 32-row tiles; m_ji rows streamed upfront.
// ---------------------------------------------------------------------------
__global__ __launch_bounds__(256, 4) void edge_kernel(
    const float* __restrict__ m_ji, const float* __restrict__ e_rbf,
    const float* __restrict__ b1, const float* __restrict__ b2,
    const float* __restrict__ b3,
    const char* __restrict__ wt4, const char* __restrict__ weT,
    float* __restrict__ out)
{
  __shared__ __align__(16) char xbA[8192];
  __shared__ __align__(16) char xbB[8192];
  const int tid = threadIdx.x, lane = tid & 63, w = tid >> 6;
  const int l15 = lane & 15, q = lane >> 4;
  const int rs = (l15 & 7) << 4;
  const size_t tb = (size_t)blockIdx.x * 32;
  const int cb = w * 32;

  bf16x8 we[2];
  #pragma unroll
  for (int ct = 0; ct < 2; ++ct)
    we[ct] = *(const bf16x8*)(weT + ((w * 2 + ct) << 10) + lane * 16);

  f32x4 mr[2][2];
  #pragma unroll
  for (int g = 0; g < 2; ++g) {
    const float* bm = m_ji + (tb + g * 16 + l15) * 128 + cb + q * 4;
    mr[g][0] = *(const f32x4*)(bm);
    mr[g][1] = *(const f32x4*)(bm + 16);
  }

  #pragma unroll
  for (int rg = 0; rg < 2; ++rg) {
    const int row = rg * 16 + l15;
    const float* ep = e_rbf + (tb + row) * 6;
    f32x4 a0 = {0.f,0.f,0.f,0.f}, a1 = {0.f,0.f,0.f,0.f};
    if (q == 0) {
      a0 = *(const f32x4*)(ep);
      float2 t = *(const float2*)(ep + 4);
      a1[0] = t.x; a1[1] = t.y;
    }
    bf16x8 ef = frag8(a0, a1);
    f32x4 acc0 = {0.f,0.f,0.f,0.f}, acc1 = {0.f,0.f,0.f,0.f};
    acc0 = __builtin_amdgcn_mfma_f32_16x16x32_bf16(we[0], ef, acc0, 0, 0, 0);
    acc1 = __builtin_amdgcn_mfma_f32_16x16x32_bf16(we[1], ef, acc1, 0, 0, 0);
    f32x4 g0 = mr[rg][0];
    f32x4 g1 = mr[rg][1];
    uint2 u0, u1;
    u0.x = pack2bf(acc0[0] * g0[0], acc0[1] * g0[1]);
    u0.y = pack2bf(acc0[2] * g0[2], acc0[3] * g0[3]);
    u1.x = pack2bf(acc1[0] * g1[0], acc1[1] * g1[1]);
    u1.y = pack2bf(acc1[2] * g1[2], acc1[3] * g1[3]);
    *(uint2*)(xbA + ((row * 256 + w * 64 + q * 8) ^ rs)) = u0;
    *(uint2*)(xbA + ((row * 256 + w * 64 + 32 + q * 8) ^ rs)) = u1;
  }
  __syncthreads();

  mlp4(xbA, xbB, wt4, b1, b2, b3, out + tb * 128, l15, q, w, rs);
}

// ---------------------------------------------------------------------------
// Prep: bf16 weights into fragment-linear layouts in d_ws (unchanged layout).
//  [0,128K):    edge W1..W4 frags [mat][ct*4+ks][lane]16B
//  [128K,256K): angle W1..W4 frags
//  [256K,272K): Wa proj frags [ct*2+ks][lane]  (K pad 42->64)
//  [272K,276K): We proj frags [ct][lane]       (K pad 6->32)
// frag(lane; n = ct*16+l15, k = ks*32+q*8+j) = W[k][n]
// ---------------------------------------------------------------------------
__global__ void prep_kernel(
    const float* __restrict__ W0, const float* __restrict__ W1,
    const float* __restrict__ W2, const float* __restrict__ W3,
    const float* __restrict__ W4, const float* __restrict__ W5,
    const float* __restrict__ W6, const float* __restrict__ W7,
    const float* __restrict__ Wa, const float* __restrict__ We,
    char* __restrict__ ws)
{
  const int gid = blockIdx.x * 256 + threadIdx.x;
  const int lane = gid & 63;
  const int l15 = lane & 15, q = lane >> 4;
  if (gid < 16384) {
    const int mat = gid >> 11;
    const int ctks = (gid & 2047) >> 6;
    const int n = (ctks >> 2) * 16 + l15;
    const int k0 = (ctks & 3) * 32 + q * 8;
    const float* W;
    switch (mat) {
      case 0: W = W0; break; case 1: W = W1; break;
      case 2: W = W2; break; case 3: W = W3; break;
      case 4: W = W4; break; case 5: W = W5; break;
      case 6: W = W6; break; default: W = W7; break;
    }
    us8 v;
    #pragma unroll
    for (int j = 0; j < 8; ++j) v[j] = f2bf_u(W[(size_t)(k0 + j) * 128 + n]);
    *(us8*)(ws + mat * 32768 + ctks * 1024 + lane * 16) = v;
  } else if (gid < 17408) {
    const int g = gid - 16384;
    const int ctks = g >> 6;
    const int n = (ctks >> 1) * 16 + l15;
    const int k0 = (ctks & 1) * 32 + q * 8;
    us8 v;
    #pragma unroll
    for (int j = 0; j < 8; ++j) {
      const int k = k0 + j;
      v[j] = (k < 42) ? f2bf_u(Wa[(size_t)k * 128 + n]) : (unsigned short)0;
    }
    *(us8*)(ws + 262144 + ctks * 1024 + lane * 16) = v;
  } else if (gid < 17920) {
    const int g = gid - 17408;
    const int ct = g >> 6;
    const int n = ct * 16 + l15;
    const int k0 = q * 8;
    us8 v;
    #pragma unroll
    for (int j = 0; j < 8; ++j) {
      const int k = k0 + j;
      v[j] = (k < 6) ? f2bf_u(We[(size_t)k * 128 + n]) : (unsigned short)0;
    }
    *(us8*)(ws + 278528 + ct * 1024 + lane * 16) = v;
  }
}

extern "C" void kernel_launch(void* const* d_in, const int* in_sizes, int n_in,
                              void* d_out, int out_size, void* d_ws, size_t ws_size,
                              hipStream_t stream) {
  (void)in_sizes; (void)n_in; (void)out_size; (void)ws_size;
  const float* m_ji  = (const float*)d_in[0];
  const float* e_rbf = (const float*)d_in[1];
  const float* a_sbf = (const float*)d_in[2];
  const int*   kj    = (const int*)d_in[4];
  const int*   ji    = (const int*)d_in[5];
  const float* We    = (const float*)d_in[6];
  const float* We1   = (const float*)d_in[7];
  const float* be1   = (const float*)d_in[8];
  const float* We2   = (const float*)d_in[9];
  const float* be2   = (const float*)d_in[10];
  const float* We3   = (const float*)d_in[11];
  const float* be3   = (const float*)d_in[12];
  const float* We4   = (const float*)d_in[13];
  const float* Wa    = (const float*)d_in[14];
  const float* Wa1   = (const float*)d_in[15];
  const float* ba1   = (const float*)d_in[16];
  const float* Wa2   = (const float*)d_in[17];
  const float* ba2   = (const float*)d_in[18];
  const float* Wa3   = (const float*)d_in[19];
  const float* ba3   = (const float*)d_in[20];
  const float* Wa4   = (const float*)d_in[21];
  char* ws = (char*)d_ws;
  float* out = (float*)d_out;
  float* out_a = out + (size_t)E_CNT * 128;

  prep_kernel<<<70, 256, 0, stream>>>(
      We1, We2, We3, We4, Wa1, Wa2, Wa3, Wa4, Wa, We, ws);
  edge_kernel<<<E_CNT / 32, 256, 0, stream>>>(
      m_ji, e_rbf, be1, be2, be3, ws, ws + 278528, out);
  angle_kernel<<<T_CNT / 32, 256, 0, stream>>>(
      m_ji, a_sbf, kj, ji, ba1, ba2, ba3, ws + 131072, ws + 262144, out_a);
}

// Round 16
// 560.257 us; speedup vs baseline: 1.2906x; 1.0423x over previous
//
#include <hip/hip_runtime.h>
#include <stdint.h>

typedef __attribute__((ext_vector_type(8))) short bf16x8;
typedef __attribute__((ext_vector_type(4))) float f32x4;
typedef __attribute__((ext_vector_type(8))) unsigned short us8;
typedef __bf16 bf16v2 __attribute__((ext_vector_type(2)));

#define T_CNT 1048576
#define E_CNT 262144

static __device__ __forceinline__ unsigned short f2bf_u(float f) {
  __bf16 h = (__bf16)f;
  return __builtin_bit_cast(unsigned short, h);
}
static __device__ __forceinline__ uint32_t pack2bf(float a, float b) {
  bf16v2 t; t[0] = (__bf16)a; t[1] = (__bf16)b;
  return __builtin_bit_cast(uint32_t, t);
}
static __device__ __forceinline__ float silu_f(float v) {
  float e = __builtin_amdgcn_exp2f(v * -1.44269504088896341f);
  return v * __builtin_amdgcn_rcpf(1.0f + e);
}
static __device__ __forceinline__ bf16x8 frag8(f32x4 a, f32x4 b) {
  union { bf16x8 v; uint32_t u[4]; } r;
  r.u[0] = pack2bf(a[0], a[1]); r.u[1] = pack2bf(a[2], a[3]);
  r.u[2] = pack2bf(b[0], b[1]); r.u[3] = pack2bf(b[2], b[3]);
  return r.v;
}

// ---------------------------------------------------------------------------
// R16 mlp4: R8's BM=64 form (wf[2][4] upfront, rg 0..3), with the final
// layer staged through LDS so global writes are full-128B-line coalesced
// (1KB per wave instruction). R15 falsified the spill theory (VGPR=48,
// excess persists) -> excess WRITE is partial-line RMW from 64B half-line
// nt-stores; this fixes the write pattern.
// xb is a single 32KB buffer: halves ping-pong as bf16 tiles for layers
// 0..2, then the whole 32KB holds the f32 [64][128] output tile (swizzled).
// ---------------------------------------------------------------------------
static __device__ __forceinline__ void mlp4(
    char* __restrict__ xb, const char* __restrict__ wt4,
    const float* __restrict__ b1, const float* __restrict__ b2,
    const float* __restrict__ b3, float* __restrict__ outT,
    int tid, int l15, int q, int w, int rs)
{
  char* xbA = xb;
  char* xbB = xb + 16384;
  const int cb = w * 32;
  const int lane16 = (l15 | (q << 4)) * 16;

  #pragma unroll
  for (int L = 0; L < 3; ++L) {
    const char* src = (L & 1) ? xbB : xbA;
    char* dst = (L & 1) ? xbA : xbB;
    bf16x8 wf[2][4];
    #pragma unroll
    for (int ct = 0; ct < 2; ++ct)
      #pragma unroll
      for (int ks = 0; ks < 4; ++ks)
        wf[ct][ks] = *(const bf16x8*)(wt4 + (L << 15) + (((w * 2 + ct) * 4 + ks) << 10) + lane16);
    const float* bp = (L == 0) ? b1 : (L == 1) ? b2 : b3;
    f32x4 bv0 = *(const f32x4*)(bp + cb + q * 4);
    f32x4 bv1 = *(const f32x4*)(bp + cb + 16 + q * 4);
    #pragma unroll
    for (int rg = 0; rg < 4; ++rg) {
      const int row = rg * 16 + l15;
      f32x4 acc0 = {0.f,0.f,0.f,0.f}, acc1 = {0.f,0.f,0.f,0.f};
      #pragma unroll
      for (int ks = 0; ks < 4; ++ks) {
        bf16x8 xf = *(const bf16x8*)(src + ((row * 256 + ks * 64 + q * 16) ^ rs));
        acc0 = __builtin_amdgcn_mfma_f32_16x16x32_bf16(wf[0][ks], xf, acc0, 0, 0, 0);
        acc1 = __builtin_amdgcn_mfma_f32_16x16x32_bf16(wf[1][ks], xf, acc1, 0, 0, 0);
      }
      uint2 u0, u1;
      u0.x = pack2bf(silu_f(acc0[0] + bv0[0]), silu_f(acc0[1] + bv0[1]));
      u0.y = pack2bf(silu_f(acc0[2] + bv0[2]), silu_f(acc0[3] + bv0[3]));
      u1.x = pack2bf(silu_f(acc1[0] + bv1[0]), silu_f(acc1[1] + bv1[1]));
      u1.y = pack2bf(silu_f(acc1[2] + bv1[2]), silu_f(acc1[3] + bv1[3]));
      *(uint2*)(dst + ((row * 256 + w * 64 + q * 8) ^ rs)) = u0;
      *(uint2*)(dst + ((row * 256 + w * 64 + 32 + q * 8) ^ rs)) = u1;
    }
    __syncthreads();
  }

  // Layer 3: compute all acc, then stage f32 tile in LDS, then coalesced out.
  {
    const char* src = xbB;  // L=3 is odd
    bf16x8 wf[2][4];
    #pragma unroll
    for (int ct = 0; ct < 2; ++ct)
      #pragma unroll
      for (int ks = 0; ks < 4; ++ks)
        wf[ct][ks] = *(const bf16x8*)(wt4 + (3 << 15) + (((w * 2 + ct) * 4 + ks) << 10) + lane16);
    f32x4 acc[4][2];
    #pragma unroll
    for (int rg = 0; rg < 4; ++rg) {
      const int row = rg * 16 + l15;
      f32x4 a0 = {0.f,0.f,0.f,0.f}, a1 = {0.f,0.f,0.f,0.f};
      #pragma unroll
      for (int ks = 0; ks < 4; ++ks) {
        bf16x8 xf = *(const bf16x8*)(src + ((row * 256 + ks * 64 + q * 16) ^ rs));
        a0 = __builtin_amdgcn_mfma_f32_16x16x32_bf16(wf[0][ks], xf, a0, 0, 0, 0);
        a1 = __builtin_amdgcn_mfma_f32_16x16x32_bf16(wf[1][ks], xf, a1, 0, 0, 0);
      }
      acc[rg][0] = a0; acc[rg][1] = a1;
    }
    __syncthreads();  // all waves done reading xbB

    // stage f32 tile [64 rows][512B], row-XOR-swizzled
    #pragma unroll
    for (int rg = 0; rg < 4; ++rg) {
      const int row = rg * 16 + l15;
      const int sw = (row & 7) << 4;
      const int b0 = row * 512 + w * 128 + q * 16;
      *(f32x4*)(xb + (b0 ^ sw)) = acc[rg][0];
      *(f32x4*)(xb + ((b0 + 64) ^ sw)) = acc[rg][1];
    }
    __syncthreads();

    // coalesced copy: wave-contiguous 1KB per instruction, full 128B lines
    #pragma unroll
    for (int i = 0; i < 8; ++i) {
      const int b = tid * 16 + i * 4096;
      const int row = b >> 9;
      const int inner = b & 511;
      f32x4 v = *(const f32x4*)(xb + ((row * 512 + inner) ^ ((row & 7) << 4)));
      __builtin_nontemporal_store(v, (f32x4*)((char*)outT + b));
    }
  }
}

// ---------------------------------------------------------------------------
// Angle branch: R8's proven proj (depth-2 gather rotation) + nt a_sbf loads.
// ---------------------------------------------------------------------------
__global__ __launch_bounds__(256, 4) void angle_kernel(
    const float* __restrict__ m_ji, const float* __restrict__ a_sbf,
    const int* __restrict__ kj, const int* __restrict__ ji,
    const float* __restrict__ b1, const float* __restrict__ b2,
    const float* __restrict__ b3,
    const char* __restrict__ wt4, const char* __restrict__ waT,
    float* __restrict__ out)
{
  __shared__ __align__(16) char xb[32768];
  char* xbA = xb;
  const int tid = threadIdx.x, lane = tid & 63, w = tid >> 6;
  const int l15 = lane & 15, q = lane >> 4;
  const int rs = (l15 & 7) << 4;
  const size_t tb = (size_t)blockIdx.x * 64;
  const int cb = w * 32;

  bf16x8 wa[2][2];
  #pragma unroll
  for (int ct = 0; ct < 2; ++ct)
    #pragma unroll
    for (int ks = 0; ks < 2; ++ks)
      wa[ct][ks] = *(const bf16x8*)(waT + (((w * 2 + ct) * 2 + ks) << 10) + lane * 16);

  int ikj[4], iji[4];
  #pragma unroll
  for (int g = 0; g < 4; ++g) {
    ikj[g] = kj[tb + g * 16 + l15];
    iji[g] = ji[tb + g * 16 + l15];
  }
  f32x4 pk[2][2], pj[2][2];
  auto gissue = [&](int g) {
    const float* bk = m_ji + (size_t)ikj[g] * 128 + cb + q * 4;
    const float* bj = m_ji + (size_t)iji[g] * 128 + cb + q * 4;
    pk[g & 1][0] = *(const f32x4*)(bk);
    pk[g & 1][1] = *(const f32x4*)(bk + 16);
    pj[g & 1][0] = *(const f32x4*)(bj);
    pj[g & 1][1] = *(const f32x4*)(bj + 16);
  };
  gissue(0); gissue(1);

  #pragma unroll
  for (int rg = 0; rg < 4; ++rg) {
    const int row = rg * 16 + l15;
    const float* ap = a_sbf + (tb + row) * 42;
    f32x4 a0, a1;
    #pragma unroll
    for (int j = 0; j < 4; ++j) {
      a0[j] = __builtin_nontemporal_load(ap + q * 8 + j);
      a1[j] = __builtin_nontemporal_load(ap + q * 8 + 4 + j);
    }
    f32x4 c0 = {0.f,0.f,0.f,0.f}, c1 = {0.f,0.f,0.f,0.f};
    if (q == 0) {
      #pragma unroll
      for (int j = 0; j < 4; ++j) {
        c0[j] = __builtin_nontemporal_load(ap + 32 + j);
        c1[j] = __builtin_nontemporal_load(ap + 36 + j);
      }
    } else if (q == 1) {
      c0[0] = __builtin_nontemporal_load(ap + 40);
      c0[1] = __builtin_nontemporal_load(ap + 41);
    }
    bf16x8 f0 = frag8(a0, a1);
    bf16x8 f1 = frag8(c0, c1);
    f32x4 acc0 = {0.f,0.f,0.f,0.f}, acc1 = {0.f,0.f,0.f,0.f};
    acc0 = __builtin_amdgcn_mfma_f32_16x16x32_bf16(wa[0][0], f0, acc0, 0, 0, 0);
    acc0 = __builtin_amdgcn_mfma_f32_16x16x32_bf16(wa[0][1], f1, acc0, 0, 0, 0);
    acc1 = __builtin_amdgcn_mfma_f32_16x16x32_bf16(wa[1][0], f0, acc1, 0, 0, 0);
    acc1 = __builtin_amdgcn_mfma_f32_16x16x32_bf16(wa[1][1], f1, acc1, 0, 0, 0);
    f32x4 g0 = pk[rg & 1][0] + pj[rg & 1][0];
    f32x4 g1 = pk[rg & 1][1] + pj[rg & 1][1];
    if (rg < 2) gissue(rg + 2);
    uint2 u0, u1;
    u0.x = pack2bf(acc0[0] * g0[0], acc0[1] * g0[1]);
    u0.y = pack2bf(acc0[2] * g0[2], acc0[3] * g0[3]);
    u1.x = pack2bf(acc1[0] * g1[0], acc1[1] * g1[1]);
    u1.y = pack2bf(acc1[2] * g1[2], acc1[3] * g1[3]);
    *(uint2*)(xbA + ((row * 256 + w * 64 + q * 8) ^ rs)) = u0;
    *(uint2*)(xbA + ((row * 256 + w * 64 + 32 + q * 8) ^ rs)) = u1;
  }
  __syncthreads();

  mlp4(xb, wt4, b1, b2, b3, out + tb * 128, tid, l15, q, w, rs);
}

// ---------------------------------------------------------------------------
// Edge branch: R8's proj + lean output path.
// ---------------------------------------------------------------------------
__global__ __launch_bounds__(256, 4) void edge_kernel(
    const float* __restrict__ m_ji, const float* __restrict__ e_rbf,
    const float* __restrict__ b1, const float* __restrict__ b2,
    const float* __restrict__ b3,
    const char* __restrict__ wt4, const char* __restrict__ weT,
    float* __restrict__ out)
{
  __shared__ __align__(16) char xb[32768];
  char* xbA = xb;
  const int tid = threadIdx.x, lane = tid & 63, w = tid >> 6;
  const int l15 = lane & 15, q = lane >> 4;
  const int rs = (l15 & 7) << 4;
  const size_t tb = (size_t)blockIdx.x * 64;
  const int cb = w * 32;

  bf16x8 we[2];
  #pragma unroll
  for (int ct = 0; ct < 2; ++ct)
    we[ct] = *(const bf16x8*)(weT + ((w * 2 + ct) << 10) + lane * 16);

  f32x4 mr[2][2];
  auto missue = [&](int g) {
    const float* bm = m_ji + (tb + g * 16 + l15) * 128 + cb + q * 4;
    mr[g & 1][0] = *(const f32x4*)(bm);
    mr[g & 1][1] = *(const f32x4*)(bm + 16);
  };
  missue(0); missue(1);

  #pragma unroll
  for (int rg = 0; rg < 4; ++rg) {
    const int row = rg * 16 + l15;
    const float* ep = e_rbf + (tb + row) * 6;
    f32x4 a0 = {0.f,0.f,0.f,0.f}, a1 = {0.f,0.f,0.f,0.f};
    if (q == 0) {
      a0 = *(const f32x4*)(ep);
      float2 t = *(const float2*)(ep + 4);
      a1[0] = t.x; a1[1] = t.y;
    }
    bf16x8 ef = frag8(a0, a1);
    f32x4 acc0 = {0.f,0.f,0.f,0.f}, acc1 = {0.f,0.f,0.f,0.f};
    acc0 = __builtin_amdgcn_mfma_f32_16x16x32_bf16(we[0], ef, acc0, 0, 0, 0);
    acc1 = __builtin_amdgcn_mfma_f32_16x16x32_bf16(we[1], ef, acc1, 0, 0, 0);
    f32x4 g0 = mr[rg & 1][0];
    f32x4 g1 = mr[rg & 1][1];
    if (rg < 2) missue(rg + 2);
    uint2 u0, u1;
    u0.x = pack2bf(acc0[0] * g0[0], acc0[1] * g0[1]);
    u0.y = pack2bf(acc0[2] * g0[2], acc0[3] * g0[3]);
    u1.x = pack2bf(acc1[0] * g1[0], acc1[1] * g1[1]);
    u1.y = pack2bf(acc1[2] * g1[2], acc1[3] * g1[3]);
    *(uint2*)(xbA + ((row * 256 + w * 64 + q * 8) ^ rs)) = u0;
    *(uint2*)(xbA + ((row * 256 + w * 64 + 32 + q * 8) ^ rs)) = u1;
  }
  __syncthreads();

  mlp4(xb, wt4, b1, b2, b3, out + tb * 128, tid, l15, q, w, rs);
}

// ---------------------------------------------------------------------------
// Prep: bf16 weights into fragment-linear layouts in d_ws (unchanged layout).
//  [0,128K):    edge W1..W4 frags [mat][ct*4+ks][lane]16B
//  [128K,256K): angle W1..W4 frags
//  [256K,272K): Wa proj frags [ct*2+ks][lane]  (K pad 42->64)
//  [272K,276K): We proj frags [ct][lane]       (K pad 6->32)
// frag(lane; n = ct*16+l15, k = ks*32+q*8+j) = W[k][n]
// ---------------------------------------------------------------------------
__global__ void prep_kernel(
    const float* __restrict__ W0, const float* __restrict__ W1,
    const float* __restrict__ W2, const float* __restrict__ W3,
    const float* __restrict__ W4, const float* __restrict__ W5,
    const float* __restrict__ W6, const float* __restrict__ W7,
    const float* __restrict__ Wa, const float* __restrict__ We,
    char* __restrict__ ws)
{
  const int gid = blockIdx.x * 256 + threadIdx.x;
  const int lane = gid & 63;
  const int l15 = lane & 15, q = lane >> 4;
  if (gid < 16384) {
    const int mat = gid >> 11;
    const int ctks = (gid & 2047) >> 6;
    const int n = (ctks >> 2) * 16 + l15;
    const int k0 = (ctks & 3) * 32 + q * 8;
    const float* W;
    switch (mat) {
      case 0: W = W0; break; case 1: W = W1; break;
      case 2: W = W2; break; case 3: W = W3; break;
      case 4: W = W4; break; case 5: W = W5; break;
      case 6: W = W6; break; default: W = W7; break;
    }
    us8 v;
    #pragma unroll
    for (int j = 0; j < 8; ++j) v[j] = f2bf_u(W[(size_t)(k0 + j) * 128 + n]);
    *(us8*)(ws + mat * 32768 + ctks * 1024 + lane * 16) = v;
  } else if (gid < 17408) {
    const int g = gid - 16384;
    const int ctks = g >> 6;
    const int n = (ctks >> 1) * 16 + l15;
    const int k0 = (ctks & 1) * 32 + q * 8;
    us8 v;
    #pragma unroll
    for (int j = 0; j < 8; ++j) {
      const int k = k0 + j;
      v[j] = (k < 42) ? f2bf_u(Wa[(size_t)k * 128 + n]) : (unsigned short)0;
    }
    *(us8*)(ws + 262144 + ctks * 1024 + lane * 16) = v;
  } else if (gid < 17920) {
    const int g = gid - 17408;
    const int ct = g >> 6;
    const int n = ct * 16 + l15;
    const int k0 = q * 8;
    us8 v;
    #pragma unroll
    for (int j = 0; j < 8; ++j) {
      const int k = k0 + j;
      v[j] = (k < 6) ? f2bf_u(We[(size_t)k * 128 + n]) : (unsigned short)0;
    }
    *(us8*)(ws + 278528 + ct * 1024 + lane * 16) = v;
  }
}

extern "C" void kernel_launch(void* const* d_in, const int* in_sizes, int n_in,
                              void* d_out, int out_size, void* d_ws, size_t ws_size,
                              hipStream_t stream) {
  (void)in_sizes; (void)n_in; (void)out_size; (void)ws_size;
  const float* m_ji  = (const float*)d_in[0];
  const float* e_rbf = (const float*)d_in[1];
  const float* a_sbf = (const float*)d_in[2];
  const int*   kj    = (const int*)d_in[4];
  const int*   ji    = (const int*)d_in[5];
  const float* We    = (const float*)d_in[6];
  const float* We1   = (const float*)d_in[7];
  const float* be1   = (const float*)d_in[8];
  const float* We2   = (const float*)d_in[9];
  const float* be2   = (const float*)d_in[10];
  const float* We3   = (const float*)d_in[11];
  const float* be3   = (const float*)d_in[12];
  const float* We4   = (const float*)d_in[13];
  const float* Wa    = (const float*)d_in[14];
  const float* Wa1   = (const float*)d_in[15];
  const float* ba1   = (const float*)d_in[16];
  const float* Wa2   = (const float*)d_in[17];
  const float* ba2   = (const float*)d_in[18];
  const float* Wa3   = (const float*)d_in[19];
  const float* ba3   = (const float*)d_in[20];
  const float* Wa4   = (const float*)d_in[21];
  char* ws = (char*)d_ws;
  float* out = (float*)d_out;
  float* out_a = out + (size_t)E_CNT * 128;

  prep_kernel<<<70, 256, 0, stream>>>(
      We1, We2, We3, We4, Wa1, Wa2, Wa3, Wa4, Wa, We, ws);
  edge_kernel<<<E_CNT / 64, 256, 0, stream>>>(
      m_ji, e_rbf, be1, be2, be3, ws, ws + 278528, out);
  angle_kernel<<<T_CNT / 64, 256, 0, stream>>>(
      m_ji, a_sbf, kj, ji, ba1, ba2, ba3, ws + 131072, ws + 262144, out_a);
}